// Round 9
// baseline (155.926 us; speedup 1.0000x reference)
//
#include <hip/hip_runtime.h>
#include <hip/hip_bf16.h>

typedef __bf16   bf16x8 __attribute__((ext_vector_type(8)));
typedef _Float16 f16x8  __attribute__((ext_vector_type(8)));
typedef _Float16 f16x4  __attribute__((ext_vector_type(4)));
typedef float    f32x4  __attribute__((ext_vector_type(4)));

#define NTOK 4096
#define CDIM 512
#define HEADS 8
#define HD 64

__device__ __forceinline__ void gload_lds16(const void* g, void* l) {
    __builtin_amdgcn_global_load_lds((const __attribute__((address_space(1))) void*)g,
                                     (__attribute__((address_space(3))) void*)l, 16, 0, 0);
}

// ---------------------------------------------------------------------------
// P1 (merged): blocks x<64: x [sb][n][c] f32 -> XT [sb][kb][c][kk] fp16.
//              blocks x>=64: Wv transpose -> wvt fp16 [s][j][k].
// ---------------------------------------------------------------------------
__global__ __launch_bounds__(256, 4) void xpose_kernel(const float* __restrict__ x1,
                                                       const float* __restrict__ x2,
                                                       const float* __restrict__ Wkv1,
                                                       const float* __restrict__ Wkv2,
                                                       _Float16* __restrict__ xt,
                                                       _Float16* __restrict__ wvt) {
    const int t = threadIdx.x, w = t >> 6, l = t & 63;

    if (blockIdx.x >= 64) {
        // ---- wtrans role ----
        if (blockIdx.z >= 8) return;
        const int s = blockIdx.x - 64;
        const float* W = (s ? Wkv2 : Wkv1);
        const int k0 = blockIdx.z * 64;
        const int j = blockIdx.y * 256 + w * 64 + l;

        f16x8 vh[8];
        #pragma unroll
        for (int q = 0; q < 64; ++q) {
            float v = W[(size_t)(k0 + q) * (2 * CDIM) + CDIM + j];
            vh[q >> 3][q & 7] = (_Float16)v;
        }
        _Float16* dh = wvt + ((size_t)s * CDIM + j) * CDIM + k0;
        #pragma unroll
        for (int q = 0; q < 8; ++q)
            *(f16x8*)&dh[q * 8] = vh[q];
        return;
    }

    // ---- xpose role ----
    const int kb = blockIdx.x, cb = blockIdx.y, sb = blockIdx.z;
    const int s = sb >> 3, b = sb & 7;
    const float* xs = (s ? x2 : x1) + (size_t)b * NTOK * CDIM
                    + (size_t)kb * 64 * CDIM + cb * 256;

    __shared__ _Float16 lds[64 * 256];

    float4 v[16];
    #pragma unroll
    for (int i = 0; i < 16; ++i) {
        const int n = 4 * i + w;
        v[i] = *(const float4*)&xs[(size_t)n * CDIM + l * 4];
    }
    #pragma unroll
    for (int i = 0; i < 16; ++i) {
        const int n = 4 * i + w;
        f16x4 p = {(_Float16)v[i].x, (_Float16)v[i].y, (_Float16)v[i].z, (_Float16)v[i].w};
        *(f16x4*)&lds[n * 256 + ((l ^ (n >> 3)) << 2)] = p;
    }
    __syncthreads();

    const int kk8 = (l & 7);
    _Float16* dst = xt + ((size_t)(sb * 64 + kb) * CDIM + cb * 256) * 64;
    #pragma unroll
    for (int q = 0; q < 8; ++q) {
        const int cw = 64 * w + 8 * q + (l >> 3);
        const int c4s = (cw >> 2) ^ kk8, c2 = cw & 3;
        const int base = (c4s << 2) + c2 + kk8 * 8 * 256;
        f16x8 o;
        #pragma unroll
        for (int j = 0; j < 8; ++j)
            o[j] = lds[base + j * 256];
        *(f16x8*)&dst[(size_t)cw * 64 + kk8 * 8] = o;
    }
}

// ---------------------------------------------------------------------------
// Gram v4: 256x256 tile, 8 waves (2M x 4N, 128x64 per wave), BK=64, split=4.
// Depth-1 prefetch (proven slot discipline, vmcnt(8)) + 4 barrier-separated
// sub-phases per K-tile: {read A-frag-group || 16 MFMA} with setprio.
// LDS 128 KiB (2 slots x (A 32K + B 32K)). 256 blocks = 1/CU, 8 waves.
// ---------------------------------------------------------------------------
__global__ __launch_bounds__(512, 2) void gram_kernel(const _Float16* __restrict__ xt,
                                                      float* __restrict__ /*unused*/,
                                                      _Float16* __restrict__ GPh) {
    const int id = blockIdx.x;                  // 256
    const int vid = (id & 7) * 32 + (id >> 3);  // XCD-contiguous: sb {2g,2g+1} on XCD g
    const int sb = vid >> 4, rest = vid & 15;
    const int split = rest >> 2, tile = rest & 3;
    const int I0 = (tile >> 1) * 256, J0 = (tile & 1) * 256;
    const _Float16* xb = xt + (size_t)sb * CDIM * NTOK;

    __shared__ _Float16 Atile[2][256 * 64];
    __shared__ _Float16 Btile[2][256 * 64];

    const int t = threadIdx.x, w = t >> 6, l = t & 63;
    const int wm = w >> 2, wn = w & 3;          // wave: M-half, N-quarter
    const int l15 = l & 15, lk = l >> 4;
    const int scol = w * 8 + (l >> 3), spos = l & 7;   // staging col/chunk

    f32x4 acc[8][4];
    #pragma unroll
    for (int f = 0; f < 8; ++f)
        #pragma unroll
        for (int g = 0; g < 4; ++g) acc[f][g] = (f32x4)(0.0f);

    auto STAGE = [&](int bufi, int it) {
        const _Float16* kbase = xb + (size_t)(split * 16 + it) * (CDIM * 64);
        #pragma unroll
        for (int r = 0; r < 4; ++r) {
            const int col = r * 64 + scol;                       // 0..255
            const int swz = ((spos ^ (col & 7)) << 3);
            gload_lds16(kbase + (size_t)(I0 + col) * 64 + swz,
                        &Atile[bufi][(r * 64 + w * 8) * 64]);
            gload_lds16(kbase + (size_t)(J0 + col) * 64 + swz,
                        &Btile[bufi][(r * 64 + w * 8) * 64]);
        }
    };

    STAGE(0, 0);
    for (int it = 0; it < 16; ++it) {
        const int cur = it & 1;
        if (it < 15) {
            STAGE(cur ^ 1, it + 1);
            asm volatile("s_waitcnt vmcnt(8)" ::: "memory");
        } else {
            asm volatile("s_waitcnt vmcnt(0)" ::: "memory");
        }
        __builtin_amdgcn_s_barrier();

        const _Float16* Ab = &Atile[cur][0];
        const _Float16* Bb = &Btile[cur][0];

        #pragma unroll
        for (int ks = 0; ks < 2; ++ks) {
            // ---- sub-phase 1: read B(ks) + A-frags 0..3, MFMA f0-3 ----
            f16x8 bfr[4], afr[4];
            #pragma unroll
            for (int g = 0; g < 4; ++g) {
                const int j = wn * 64 + g * 16 + l15;
                bfr[g] = *(const f16x8*)&Bb[j * 64 + ((ks * 4 + lk) ^ (j & 7)) * 8];
            }
            #pragma unroll
            for (int q = 0; q < 4; ++q) {
                const int i = wm * 128 + q * 16 + l15;
                afr[q] = *(const f16x8*)&Ab[i * 64 + ((ks * 4 + lk) ^ (i & 7)) * 8];
            }
            __builtin_amdgcn_s_setprio(1);
            #pragma unroll
            for (int q = 0; q < 4; ++q)
                #pragma unroll
                for (int g = 0; g < 4; ++g)
                    acc[q][g] = __builtin_amdgcn_mfma_f32_16x16x32_f16(afr[q], bfr[g], acc[q][g], 0, 0, 0);
            __builtin_amdgcn_s_setprio(0);
            __builtin_amdgcn_s_barrier();

            // ---- sub-phase 2: read A-frags 4..7 (B kept), MFMA f4-7 ----
            #pragma unroll
            for (int q = 0; q < 4; ++q) {
                const int i = wm * 128 + (q + 4) * 16 + l15;
                afr[q] = *(const f16x8*)&Ab[i * 64 + ((ks * 4 + lk) ^ (i & 7)) * 8];
            }
            __builtin_amdgcn_s_setprio(1);
            #pragma unroll
            for (int q = 0; q < 4; ++q)
                #pragma unroll
                for (int g = 0; g < 4; ++g)
                    acc[q + 4][g] = __builtin_amdgcn_mfma_f32_16x16x32_f16(afr[q], bfr[g], acc[q + 4][g], 0, 0, 0);
            __builtin_amdgcn_s_setprio(0);
            __builtin_amdgcn_s_barrier();
        }
    }

    _Float16* Gout = GPh + ((size_t)split * 16 + sb) * CDIM * CDIM;
    #pragma unroll
    for (int f = 0; f < 8; ++f)
        #pragma unroll
        for (int g = 0; g < 4; ++g) {
            const int row0 = I0 + wm * 128 + f * 16 + lk * 4;
            const int col  = J0 + wn * 64 + g * 16 + l15;
            #pragma unroll
            for (int r = 0; r < 4; ++r)
                Gout[(size_t)(row0 + r) * CDIM + col] = (_Float16)acc[f][g][r];
        }
}

// ---------------------------------------------------------------------------
// T-partials: TP[ks2][sb] = (G0+G1+G2+G3)(k-range) @ Wv, single fp16 MFMA.
// 512 blocks (2/CU), XCD-aligned with gram writer. 4-partial sum in fp16.
// ---------------------------------------------------------------------------
__global__ __launch_bounds__(256) void t_kernel(const _Float16* __restrict__ GPh,
                                                const _Float16* __restrict__ wvt,
                                                _Float16* __restrict__ TP) {
    const int id = blockIdx.x;                  // 512
    const int vid = (id & 7) * 64 + (id >> 3);
    const int sb = vid >> 5, rest = vid & 31;
    const int ks2 = rest >> 4, tile = rest & 15;
    const int s = sb >> 3;
    const int I0 = (tile >> 2) * 128, J0 = (tile & 3) * 128;
    const _Float16* G0 = GPh + (size_t)sb * CDIM * CDIM;
    const _Float16* G1 = GPh + ((size_t)16 + sb) * CDIM * CDIM;
    const _Float16* G2 = GPh + ((size_t)32 + sb) * CDIM * CDIM;
    const _Float16* G3 = GPh + ((size_t)48 + sb) * CDIM * CDIM;
    const _Float16* Bv = wvt + (size_t)s * CDIM * CDIM;

    __shared__ _Float16 Ah[128 * 64];
    __shared__ _Float16 Jh[128 * 64];

    const int t = threadIdx.x, w = t >> 6, l = t & 63;
    const int wm = w >> 1, wn = w & 1, l15 = l & 15, lk = l >> 4;
    const int colr = w * 8 + (l >> 3), pos = l & 7;

    f32x4 acc[4][4];
    #pragma unroll
    for (int f = 0; f < 4; ++f)
        #pragma unroll
        for (int g = 0; g < 4; ++g) acc[f][g] = (f32x4)(0.0f);

    for (int it = 0; it < 4; ++it) {
        const int k0 = ks2 * 256 + it * 64;
        __syncthreads();
        #pragma unroll
        for (int r = 0; r < 4; ++r) {
            const int col = r * 32 + colr;
            const int swz = ((pos ^ (col & 7)) << 3);
            gload_lds16(Bv + (size_t)(J0 + col) * CDIM + k0 + swz, &Jh[r * 2048 + w * 512]);
        }
        #pragma unroll
        for (int r = 0; r < 4; ++r) {
            const int i = r * 32 + (t >> 3), ch = t & 7;
            const size_t off = (size_t)(I0 + i) * CDIM + k0 + ch * 8;
            f16x8 a0 = *(const f16x8*)&G0[off];
            f16x8 a1 = *(const f16x8*)&G1[off];
            f16x8 a2 = *(const f16x8*)&G2[off];
            f16x8 a3 = *(const f16x8*)&G3[off];
            f16x8 sum = (a0 + a1) + (a2 + a3);
            *(f16x8*)&Ah[i * 64 + ((ch ^ (i & 7)) << 3)] = sum;
        }
        __syncthreads();
        __builtin_amdgcn_s_setprio(1);
        #pragma unroll
        for (int ks = 0; ks < 2; ++ks) {
            f16x8 a[4], bb[4];
            #pragma unroll
            for (int f = 0; f < 4; ++f) {
                const int i = wm * 64 + f * 16 + l15;
                a[f] = *(const f16x8*)&Ah[i * 64 + ((ks * 4 + lk) ^ (i & 7)) * 8];
            }
            #pragma unroll
            for (int g = 0; g < 4; ++g) {
                const int j = wn * 64 + g * 16 + l15;
                bb[g] = *(const f16x8*)&Jh[j * 64 + ((ks * 4 + lk) ^ (j & 7)) * 8];
            }
            #pragma unroll
            for (int f = 0; f < 4; ++f)
                #pragma unroll
                for (int g = 0; g < 4; ++g)
                    acc[f][g] = __builtin_amdgcn_mfma_f32_16x16x32_f16(a[f], bb[g], acc[f][g], 0, 0, 0);
        }
        __builtin_amdgcn_s_setprio(0);
    }

    _Float16* Tb = TP + ((size_t)ks2 * 16 + sb) * CDIM * CDIM;
    #pragma unroll
    for (int f = 0; f < 4; ++f)
        #pragma unroll
        for (int g = 0; g < 4; ++g) {
            const int row0 = I0 + wm * 64 + f * 16 + lk * 4;
            const int col  = J0 + wn * 64 + g * 16 + l15;
            #pragma unroll
            for (int r = 0; r < 4; ++r)
                Tb[(size_t)(row0 + r) * CDIM + col] = (_Float16)acc[f][g][r];
        }
}

// ---------------------------------------------------------------------------
// ctx GEMM, K-split by 4: CP[kq][sb][h] = partial Wk_h^T (TP0+TP1)_h
// ---------------------------------------------------------------------------
__global__ __launch_bounds__(256) void ctx_gemm_kernel(const _Float16* __restrict__ TP,
                                                       const float* __restrict__ Wkv1,
                                                       const float* __restrict__ Wkv2,
                                                       float* __restrict__ CP) {
    const int h = blockIdx.x, sb = blockIdx.y, kq = blockIdx.z;
    const int s = sb >> 3;
    const float* W  = (s == 0 ? Wkv1 : Wkv2);
    const _Float16* T0 = TP + (size_t)sb * CDIM * CDIM;
    const _Float16* T1 = TP + ((size_t)16 + sb) * CDIM * CDIM;

    __shared__ float Kt[64][65];
    __shared__ float Tt[64][65];

    const int t = threadIdx.x;
    const int td = t >> 4, te = t & 15;
    float acc[4][4] = {};

    for (int it = 0; it < 2; ++it) {
        const int kc = kq * 128 + it * 64;
        __syncthreads();
        for (int i = 0; i < 16; ++i) {
            const int idx = t + i * 256;
            const int r = idx >> 6, cc = idx & 63;
            Kt[r][cc] = W[(size_t)(kc + r) * (2 * CDIM) + h * HD + cc];
            Tt[r][cc] = (float)T0[(size_t)(kc + r) * CDIM + h * HD + cc]
                      + (float)T1[(size_t)(kc + r) * CDIM + h * HD + cc];
        }
        __syncthreads();
        for (int k = 0; k < 64; ++k) {
            float a[4], bb[4];
            #pragma unroll
            for (int i = 0; i < 4; ++i) a[i] = Kt[k][td * 4 + i];
            #pragma unroll
            for (int j = 0; j < 4; ++j) bb[j] = Tt[k][te * 4 + j];
            #pragma unroll
            for (int i = 0; i < 4; ++i)
                #pragma unroll
                for (int j = 0; j < 4; ++j) acc[i][j] += a[i] * bb[j];
        }
    }
    float* out = CP + (size_t)(((kq * 16 + sb) * HEADS) + h) * HD * HD;
    for (int i = 0; i < 4; ++i)
        for (int j = 0; j < 4; ++j)
            out[(size_t)(td * 4 + i) * HD + te * 4 + j] = acc[i][j];
}

// ---------------------------------------------------------------------------
// ctx finish: sum 4 partials, scale, softmax over d -> smT fp16 [sb][h][e][d]
// ---------------------------------------------------------------------------
__global__ __launch_bounds__(256) void ctx_fin_kernel(const float* __restrict__ CP,
                                                      _Float16* __restrict__ smT) {
    const int h = blockIdx.x, sb = blockIdx.y;

    __shared__ float ctxs[64][65];
    __shared__ float mred[64], sred[64];

    const int t = threadIdx.x;
    const float scale = 0.125f;
    #pragma unroll
    for (int i = 0; i < 4; ++i) {
        const int idx4 = t + i * 256;
        const int d = idx4 >> 4, e4 = idx4 & 15;
        f32x4 sum = (f32x4)(0.0f);
        #pragma unroll
        for (int kq = 0; kq < 4; ++kq) {
            const float* p = CP + (size_t)(((kq * 16 + sb) * HEADS) + h) * HD * HD;
            f32x4 v = *(const f32x4*)&p[d * HD + e4 * 4];
            sum += v;
        }
        *(f32x4*)&ctxs[d][e4 * 4] = sum * scale;
    }
    __syncthreads();
    if (t < 64) {
        float m = -1e30f;
        for (int d = 0; d < 64; ++d) m = fmaxf(m, ctxs[d][t]);
        float ssum = 0.f;
        for (int d = 0; d < 64; ++d) ssum += expf(ctxs[d][t] - m);
        mred[t] = m;
        sred[t] = 1.0f / ssum;
    }
    __syncthreads();
    _Float16* smout = smT + (size_t)(sb * HEADS + h) * HD * HD;   // [e][d]
    #pragma unroll
    for (int i = 0; i < 16; ++i) {
        const int idx = t + i * 256;
        const int e = idx >> 6, d = idx & 63;
        smout[e * HD + d] = (_Float16)(expf(ctxs[d][e] - mred[e]) * sred[e]);
    }
}

// ---------------------------------------------------------------------------
// out: out_s[n, h*64+e] = sum_d x_s[n, h*64+d] * sm[1-s][h][d][e], fp16 MFMA
// ---------------------------------------------------------------------------
__global__ __launch_bounds__(256) void out_kernel(const float* __restrict__ x1,
                                                  const float* __restrict__ x2,
                                                  const _Float16* __restrict__ smT,
                                                  float* __restrict__ out) {
    const int id = blockIdx.x;                   // 4096
    const int vid = (id & 7) * 512 + (id >> 3);  // h-groups co-XCD
    const int h = vid & 7, nt = (vid >> 3) & 31, sb = vid >> 8;
    const int s = sb >> 3, b = sb & 7;
    const float* xs = (s ? x2 : x1) + (size_t)b * NTOK * CDIM;
    const _Float16* sm = smT + (size_t)((((1 - s) * 8 + b) * HEADS) + h) * HD * HD;
    const int n0 = nt * 128;

    __shared__ _Float16 Axt[128 * 64];
    __shared__ _Float16 Bsm[64 * 64];

    const int t = threadIdx.x, w = t >> 6, l = t & 63;
    const int l15 = l & 15, lk = l >> 4;

    #pragma unroll
    for (int r = 0; r < 2; ++r) {
        const int e = r * 32 + w * 8 + (l >> 3), pos = l & 7;
        gload_lds16(sm + (size_t)e * HD + ((pos ^ (e & 7)) << 3), &Bsm[r * 2048 + w * 512]);
    }
    #pragma unroll
    for (int p = 0; p < 8; ++p) {
        const int row = p * 16 + (t >> 4), f4c = t & 15;
        float4 u = *(const float4*)&xs[(size_t)(n0 + row) * CDIM + h * HD + f4c * 4];
        f16x4 q = {(_Float16)u.x, (_Float16)u.y, (_Float16)u.z, (_Float16)u.w};
        const int byte = row * 128 + (((f4c >> 1) ^ (row & 7)) << 4) + ((f4c & 1) << 3);
        *(f16x4*)((char*)Axt + byte) = q;
    }
    __syncthreads();

    f32x4 acc[2][4];
    #pragma unroll
    for (int m = 0; m < 2; ++m)
        #pragma unroll
        for (int g = 0; g < 4; ++g) acc[m][g] = (f32x4)(0.0f);

    #pragma unroll
    for (int ks = 0; ks < 2; ++ks) {
        f16x8 a[2], bb[4];
        #pragma unroll
        for (int m = 0; m < 2; ++m) {
            const int row = w * 32 + m * 16 + l15;
            a[m] = *(const f16x8*)((char*)Axt + row * 128 + (((ks * 4 + lk) ^ (row & 7)) << 4));
        }
        #pragma unroll
        for (int g = 0; g < 4; ++g) {
            const int e = g * 16 + l15;
            bb[g] = *(const f16x8*)((char*)Bsm + e * 128 + (((ks * 4 + lk) ^ (e & 7)) << 4));
        }
        #pragma unroll
        for (int m = 0; m < 2; ++m)
            #pragma unroll
            for (int g = 0; g < 4; ++g)
                acc[m][g] = __builtin_amdgcn_mfma_f32_16x16x32_f16(a[m], bb[g], acc[m][g], 0, 0, 0);
    }

    float* ob = out + (size_t)s * (8ULL * NTOK * CDIM) + (size_t)b * NTOK * CDIM;
    #pragma unroll
    for (int m = 0; m < 2; ++m)
        #pragma unroll
        for (int g = 0; g < 4; ++g) {
            const int row0 = n0 + w * 32 + m * 16 + lk * 4;
            const int col  = h * HD + g * 16 + l15;
            #pragma unroll
            for (int r = 0; r < 4; ++r)
                ob[(size_t)(row0 + r) * CDIM + col] = acc[m][g][r];
        }
}

// ---------------------------------------------------------------------------
extern "C" void kernel_launch(void* const* d_in, const int* in_sizes, int n_in,
                              void* d_out, int out_size, void* d_ws, size_t ws_size,
                              hipStream_t stream) {
    const float* x1   = (const float*)d_in[0];
    const float* x2   = (const float*)d_in[1];
    const float* Wkv1 = (const float*)d_in[2];
    const float* Wkv2 = (const float*)d_in[3];
    float* out = (float*)d_out;

    char* base = (char*)d_out;
    _Float16* XT   = (_Float16*)(base + 0);            // 64 MiB [sb][kb][c][64]
    _Float16* WVT  = (_Float16*)(base + 67108864);     // 1 MiB fp16 [s][j][k]
    _Float16* GPh  = (_Float16*)(base + 68157440);     // 32 MiB fp16 (4 partials)
    _Float16* TP   = (_Float16*)(base + 101711872);    // 16 MiB fp16 (2 partials)
    float*    CP   = (float*)(base + 118489088);       // 8 MiB f32 (4 partials)
    _Float16* SMT  = (_Float16*)d_ws;                  // 1 MiB

    hipLaunchKernelGGL(xpose_kernel, dim3(66, 2, 16), dim3(256), 0, stream,
                       x1, x2, Wkv1, Wkv2, XT, WVT);
    hipLaunchKernelGGL(gram_kernel, dim3(256), dim3(512), 0, stream, XT, (float*)nullptr, GPh);
    hipLaunchKernelGGL(t_kernel, dim3(512), dim3(256), 0, stream, GPh, WVT, TP);
    hipLaunchKernelGGL(ctx_gemm_kernel, dim3(8, 16, 4), dim3(256), 0, stream,
                       TP, Wkv1, Wkv2, CP);
    hipLaunchKernelGGL(ctx_fin_kernel, dim3(8, 16), dim3(256), 0, stream, CP, SMT);
    hipLaunchKernelGGL(out_kernel, dim3(4096), dim3(256), 0, stream, x1, x2, SMT, out);
}

// Round 10
// 153.742 us; speedup vs baseline: 1.0142x; 1.0142x over previous
//
#include <hip/hip_runtime.h>
#include <hip/hip_bf16.h>

typedef __bf16   bf16x8 __attribute__((ext_vector_type(8)));
typedef _Float16 f16x8  __attribute__((ext_vector_type(8)));
typedef _Float16 f16x4  __attribute__((ext_vector_type(4)));
typedef float    f32x4  __attribute__((ext_vector_type(4)));

#define NTOK 4096
#define CDIM 512
#define HEADS 8
#define HD 64

__device__ __forceinline__ void gload_lds16(const void* g, void* l) {
    __builtin_amdgcn_global_load_lds((const __attribute__((address_space(1))) void*)g,
                                     (__attribute__((address_space(3))) void*)l, 16, 0, 0);
}

// ---------------------------------------------------------------------------
// P1 (merged): blocks x<64: x [sb][n][c] f32 -> XT [sb][kb][c][kk] fp16.
//              blocks x>=64 (y<2,z<8): Wv transpose -> wvt fp16 [s][j][k].
// 64n x 128c tile, 16 KiB LDS, 6 blocks/CU for latency hiding.
// ---------------------------------------------------------------------------
__global__ __launch_bounds__(256, 6) void xpose_kernel(const float* __restrict__ x1,
                                                       const float* __restrict__ x2,
                                                       const float* __restrict__ Wkv1,
                                                       const float* __restrict__ Wkv2,
                                                       _Float16* __restrict__ xt,
                                                       _Float16* __restrict__ wvt) {
    const int t = threadIdx.x, w = t >> 6, l = t & 63;

    if (blockIdx.x >= 64) {
        // ---- wtrans role ----
        if (blockIdx.y >= 2 || blockIdx.z >= 8) return;
        const int s = blockIdx.x - 64;
        const float* W = (s ? Wkv2 : Wkv1);
        const int k0 = blockIdx.z * 64;
        const int j = blockIdx.y * 256 + w * 64 + l;

        f16x8 vh[8];
        #pragma unroll
        for (int q = 0; q < 64; ++q) {
            float v = W[(size_t)(k0 + q) * (2 * CDIM) + CDIM + j];
            vh[q >> 3][q & 7] = (_Float16)v;
        }
        _Float16* dh = wvt + ((size_t)s * CDIM + j) * CDIM + k0;
        #pragma unroll
        for (int q = 0; q < 8; ++q)
            *(f16x8*)&dh[q * 8] = vh[q];
        return;
    }

    // ---- xpose role ----
    const int kb = blockIdx.x, cb = blockIdx.y, sb = blockIdx.z;
    const int s = sb >> 3, b = sb & 7;
    const float* xs = (s ? x2 : x1) + (size_t)b * NTOK * CDIM
                    + (size_t)kb * 64 * CDIM + cb * 128;

    __shared__ _Float16 lds[64 * 128];

    // Phase A: 8 float4 per thread, all loads issued before LDS writes.
    const int nsub = l >> 5, c4 = l & 31;
    float4 v[8];
    #pragma unroll
    for (int i = 0; i < 8; ++i) {
        const int n = 8 * i + 2 * w + nsub;
        v[i] = *(const float4*)&xs[(size_t)n * CDIM + c4 * 4];
    }
    #pragma unroll
    for (int i = 0; i < 8; ++i) {
        const int n = 8 * i + 2 * w + nsub;
        f16x4 p = {(_Float16)v[i].x, (_Float16)v[i].y, (_Float16)v[i].z, (_Float16)v[i].w};
        *(f16x4*)&lds[n * 128 + ((c4 ^ (n >> 3)) << 2)] = p;
    }
    __syncthreads();

    // Phase B: per q-instr the wave's 64 stores are byte-contiguous (1 KiB).
    const int kk8 = l & 7;
    _Float16* dst = xt + ((size_t)(sb * 64 + kb) * CDIM + cb * 128) * 64;
    #pragma unroll
    for (int q = 0; q < 4; ++q) {
        const int cw = w * 32 + q * 8 + (l >> 3);
        const int base = kk8 * 8 * 128 + (((cw >> 2) ^ kk8) << 2) + (cw & 3);
        f16x8 o;
        #pragma unroll
        for (int j = 0; j < 8; ++j)
            o[j] = lds[base + j * 128];
        *(f16x8*)&dst[(size_t)cw * 64 + kk8 * 8] = o;
    }
}

// ---------------------------------------------------------------------------
// Gram: GPh[split][sb] = xt(k-half)^T xt(k-half), fp16 MFMA, fp16 output.
// 512 blocks (2/CU), 2-phase pipeline, counted vmcnt(8), setprio on MFMA.
// ---------------------------------------------------------------------------
__global__ __launch_bounds__(256) void gram_kernel(const _Float16* __restrict__ xt,
                                                   _Float16* __restrict__ GPh) {
    const int id = blockIdx.x;                  // 512
    const int vid = (id & 7) * 64 + (id >> 3);  // XCD-contiguous
    const int sb = vid >> 5, rest = vid & 31;
    const int split = rest >> 4, tile = rest & 15;
    const int I0 = (tile >> 2) * 128, J0 = (tile & 3) * 128;
    const _Float16* xb = xt + (size_t)sb * CDIM * NTOK;

    __shared__ _Float16 Ih[2][128 * 64];
    __shared__ _Float16 Jh[2][128 * 64];

    const int t = threadIdx.x, w = t >> 6, l = t & 63;
    const int wm = w >> 1, wn = w & 1, l15 = l & 15, lk = l >> 4;
    const int colr = w * 8 + (l >> 3), pos = l & 7;

    f32x4 acc[4][4];
    #pragma unroll
    for (int f = 0; f < 4; ++f)
        #pragma unroll
        for (int g = 0; g < 4; ++g) acc[f][g] = (f32x4)(0.0f);

    auto STAGE = [&](int bufi, int it) {
        const _Float16* kb = xb + (size_t)(split * 32 + it) * CDIM * 64;
        #pragma unroll
        for (int r = 0; r < 4; ++r) {
            const int colw = r * 32 + colr;
            const int swz = ((pos ^ (colw & 7)) << 3);
            gload_lds16(kb + (size_t)(I0 + colw) * 64 + swz, &Ih[bufi][r * 2048 + w * 512]);
            gload_lds16(kb + (size_t)(J0 + colw) * 64 + swz, &Jh[bufi][r * 2048 + w * 512]);
        }
    };

    STAGE(0, 0);
    for (int it = 0; it < 32; ++it) {
        const int cur = it & 1;
        if (it < 31) {
            STAGE(cur ^ 1, it + 1);
            asm volatile("s_waitcnt vmcnt(8)" ::: "memory");
        } else {
            asm volatile("s_waitcnt vmcnt(0)" ::: "memory");
        }
        __builtin_amdgcn_s_barrier();

        const _Float16* Ib = &Ih[cur][0];
        const _Float16* Jb = &Jh[cur][0];
        __builtin_amdgcn_s_setprio(1);
        #pragma unroll
        for (int ks = 0; ks < 2; ++ks) {
            f16x8 a[4], bb[4];
            #pragma unroll
            for (int f = 0; f < 4; ++f) {
                const int i = wm * 64 + f * 16 + l15;
                a[f] = *(const f16x8*)&Ib[i * 64 + ((ks * 4 + lk) ^ (i & 7)) * 8];
            }
            #pragma unroll
            for (int g = 0; g < 4; ++g) {
                const int j = wn * 64 + g * 16 + l15;
                bb[g] = *(const f16x8*)&Jb[j * 64 + ((ks * 4 + lk) ^ (j & 7)) * 8];
            }
            #pragma unroll
            for (int f = 0; f < 4; ++f)
                #pragma unroll
                for (int g = 0; g < 4; ++g)
                    acc[f][g] = __builtin_amdgcn_mfma_f32_16x16x32_f16(a[f], bb[g], acc[f][g], 0, 0, 0);
        }
        __builtin_amdgcn_s_setprio(0);
        __builtin_amdgcn_s_barrier();
    }

    _Float16* Gout = GPh + ((size_t)split * 16 + sb) * CDIM * CDIM;
    #pragma unroll
    for (int f = 0; f < 4; ++f)
        #pragma unroll
        for (int g = 0; g < 4; ++g) {
            const int row0 = I0 + wm * 64 + f * 16 + lk * 4;
            const int col  = J0 + wn * 64 + g * 16 + l15;
            #pragma unroll
            for (int r = 0; r < 4; ++r)
                Gout[(size_t)(row0 + r) * CDIM + col] = (_Float16)acc[f][g][r];
        }
}

// ---------------------------------------------------------------------------
// T-partials: TP[ks2][sb] = (GPh0+GPh1)(k-range) @ Wv, single fp16 MFMA.
// 512 blocks (2/CU), XCD-aligned with gram's writer so G reads hit local L2.
// ---------------------------------------------------------------------------
__global__ __launch_bounds__(256) void t_kernel(const _Float16* __restrict__ GPh,
                                                const _Float16* __restrict__ wvt,
                                                _Float16* __restrict__ TP) {
    const int id = blockIdx.x;                  // 512
    const int vid = (id & 7) * 64 + (id >> 3);  // same XCD map as gram
    const int sb = vid >> 5, rest = vid & 31;
    const int ks2 = rest >> 4, tile = rest & 15;
    const int s = sb >> 3;
    const int I0 = (tile >> 2) * 128, J0 = (tile & 3) * 128;
    const _Float16* G0 = GPh + (size_t)sb * CDIM * CDIM;
    const _Float16* G1 = GPh + ((size_t)16 + sb) * CDIM * CDIM;
    const _Float16* Bv = wvt + (size_t)s * CDIM * CDIM;

    __shared__ _Float16 Ah[128 * 64];
    __shared__ _Float16 Jh[128 * 64];

    const int t = threadIdx.x, w = t >> 6, l = t & 63;
    const int wm = w >> 1, wn = w & 1, l15 = l & 15, lk = l >> 4;
    const int colr = w * 8 + (l >> 3), pos = l & 7;

    f32x4 acc[4][4];
    #pragma unroll
    for (int f = 0; f < 4; ++f)
        #pragma unroll
        for (int g = 0; g < 4; ++g) acc[f][g] = (f32x4)(0.0f);

    for (int it = 0; it < 4; ++it) {
        const int k0 = ks2 * 256 + it * 64;
        __syncthreads();
        // B stage first: async gloads fly while A-stage does its work
        #pragma unroll
        for (int r = 0; r < 4; ++r) {
            const int col = r * 32 + colr;
            const int swz = ((pos ^ (col & 7)) << 3);
            gload_lds16(Bv + (size_t)(J0 + col) * CDIM + k0 + swz, &Jh[r * 2048 + w * 512]);
        }
        // A stage: sum the two fp16 Gram partials, store swizzled
        #pragma unroll
        for (int r = 0; r < 4; ++r) {
            const int i = r * 32 + (t >> 3), ch = t & 7;
            const size_t off = (size_t)(I0 + i) * CDIM + k0 + ch * 8;
            f16x8 a0 = *(const f16x8*)&G0[off];
            f16x8 a1 = *(const f16x8*)&G1[off];
            f16x8 sum = a0 + a1;
            *(f16x8*)&Ah[i * 64 + ((ch ^ (i & 7)) << 3)] = sum;
        }
        __syncthreads();
        __builtin_amdgcn_s_setprio(1);
        #pragma unroll
        for (int ks = 0; ks < 2; ++ks) {
            f16x8 a[4], bb[4];
            #pragma unroll
            for (int f = 0; f < 4; ++f) {
                const int i = wm * 64 + f * 16 + l15;
                a[f] = *(const f16x8*)&Ah[i * 64 + ((ks * 4 + lk) ^ (i & 7)) * 8];
            }
            #pragma unroll
            for (int g = 0; g < 4; ++g) {
                const int j = wn * 64 + g * 16 + l15;
                bb[g] = *(const f16x8*)&Jh[j * 64 + ((ks * 4 + lk) ^ (j & 7)) * 8];
            }
            #pragma unroll
            for (int f = 0; f < 4; ++f)
                #pragma unroll
                for (int g = 0; g < 4; ++g)
                    acc[f][g] = __builtin_amdgcn_mfma_f32_16x16x32_f16(a[f], bb[g], acc[f][g], 0, 0, 0);
        }
        __builtin_amdgcn_s_setprio(0);
    }

    _Float16* Tb = TP + ((size_t)ks2 * 16 + sb) * CDIM * CDIM;
    #pragma unroll
    for (int f = 0; f < 4; ++f)
        #pragma unroll
        for (int g = 0; g < 4; ++g) {
            const int row0 = I0 + wm * 64 + f * 16 + lk * 4;
            const int col  = J0 + wn * 64 + g * 16 + l15;
            #pragma unroll
            for (int r = 0; r < 4; ++r)
                Tb[(size_t)(row0 + r) * CDIM + col] = (_Float16)acc[f][g][r];
        }
}

// ---------------------------------------------------------------------------
// ctx GEMM, K-split by 4: CP[kq][sb][h] = partial Wk_h^T (TP0+TP1)_h
// ---------------------------------------------------------------------------
__global__ __launch_bounds__(256) void ctx_gemm_kernel(const _Float16* __restrict__ TP,
                                                       const float* __restrict__ Wkv1,
                                                       const float* __restrict__ Wkv2,
                                                       float* __restrict__ CP) {
    const int h = blockIdx.x, sb = blockIdx.y, kq = blockIdx.z;
    const int s = sb >> 3;
    const float* W  = (s == 0 ? Wkv1 : Wkv2);
    const _Float16* T0 = TP + (size_t)sb * CDIM * CDIM;
    const _Float16* T1 = TP + ((size_t)16 + sb) * CDIM * CDIM;

    __shared__ float Kt[64][65];
    __shared__ float Tt[64][65];

    const int t = threadIdx.x;
    const int td = t >> 4, te = t & 15;
    float acc[4][4] = {};

    for (int it = 0; it < 2; ++it) {
        const int kc = kq * 128 + it * 64;
        __syncthreads();
        for (int i = 0; i < 16; ++i) {
            const int idx = t + i * 256;
            const int r = idx >> 6, cc = idx & 63;
            Kt[r][cc] = W[(size_t)(kc + r) * (2 * CDIM) + h * HD + cc];
            Tt[r][cc] = (float)T0[(size_t)(kc + r) * CDIM + h * HD + cc]
                      + (float)T1[(size_t)(kc + r) * CDIM + h * HD + cc];
        }
        __syncthreads();
        for (int k = 0; k < 64; ++k) {
            float a[4], bb[4];
            #pragma unroll
            for (int i = 0; i < 4; ++i) a[i] = Kt[k][td * 4 + i];
            #pragma unroll
            for (int j = 0; j < 4; ++j) bb[j] = Tt[k][te * 4 + j];
            #pragma unroll
            for (int i = 0; i < 4; ++i)
                #pragma unroll
                for (int j = 0; j < 4; ++j) acc[i][j] += a[i] * bb[j];
        }
    }
    float* out = CP + (size_t)(((kq * 16 + sb) * HEADS) + h) * HD * HD;
    for (int i = 0; i < 4; ++i)
        for (int j = 0; j < 4; ++j)
            out[(size_t)(td * 4 + i) * HD + te * 4 + j] = acc[i][j];
}

// ---------------------------------------------------------------------------
// ctx finish: sum 4 partials, scale, softmax over d -> smT fp16 [sb][h][e][d]
// ---------------------------------------------------------------------------
__global__ __launch_bounds__(256) void ctx_fin_kernel(const float* __restrict__ CP,
                                                      _Float16* __restrict__ smT) {
    const int h = blockIdx.x, sb = blockIdx.y;

    __shared__ float ctxs[64][65];
    __shared__ float mred[64], sred[64];

    const int t = threadIdx.x;
    const float scale = 0.125f;
    #pragma unroll
    for (int i = 0; i < 4; ++i) {
        const int idx4 = t + i * 256;
        const int d = idx4 >> 4, e4 = idx4 & 15;
        f32x4 sum = (f32x4)(0.0f);
        #pragma unroll
        for (int kq = 0; kq < 4; ++kq) {
            const float* p = CP + (size_t)(((kq * 16 + sb) * HEADS) + h) * HD * HD;
            f32x4 v = *(const f32x4*)&p[d * HD + e4 * 4];
            sum += v;
        }
        *(f32x4*)&ctxs[d][e4 * 4] = sum * scale;
    }
    __syncthreads();
    if (t < 64) {
        float m = -1e30f;
        for (int d = 0; d < 64; ++d) m = fmaxf(m, ctxs[d][t]);
        float ssum = 0.f;
        for (int d = 0; d < 64; ++d) ssum += expf(ctxs[d][t] - m);
        mred[t] = m;
        sred[t] = 1.0f / ssum;
    }
    __syncthreads();
    _Float16* smout = smT + (size_t)(sb * HEADS + h) * HD * HD;   // [e][d]
    #pragma unroll
    for (int i = 0; i < 16; ++i) {
        const int idx = t + i * 256;
        const int e = idx >> 6, d = idx & 63;
        smout[e * HD + d] = (_Float16)(expf(ctxs[d][e] - mred[e]) * sred[e]);
    }
}

// ---------------------------------------------------------------------------
// out: out_s[n, h*64+e] = sum_d x_s[n, h*64+d] * sm[1-s][h][d][e], fp16 MFMA
// ---------------------------------------------------------------------------
__global__ __launch_bounds__(256) void out_kernel(const float* __restrict__ x1,
                                                  const float* __restrict__ x2,
                                                  const _Float16* __restrict__ smT,
                                                  float* __restrict__ out) {
    const int id = blockIdx.x;                   // 4096
    const int vid = (id & 7) * 512 + (id >> 3);  // h-groups co-XCD
    const int h = vid & 7, nt = (vid >> 3) & 31, sb = vid >> 8;
    const int s = sb >> 3, b = sb & 7;
    const float* xs = (s ? x2 : x1) + (size_t)b * NTOK * CDIM;
    const _Float16* sm = smT + (size_t)((((1 - s) * 8 + b) * HEADS) + h) * HD * HD;
    const int n0 = nt * 128;

    __shared__ _Float16 Axt[128 * 64];   // [n][d] swizzled
    __shared__ _Float16 Bsm[64 * 64];    // [e][d] swizzled

    const int t = threadIdx.x, w = t >> 6, l = t & 63;
    const int l15 = l & 15, lk = l >> 4;

    // B stage via gl_lds (2 rounds)
    #pragma unroll
    for (int r = 0; r < 2; ++r) {
        const int e = r * 32 + w * 8 + (l >> 3), pos = l & 7;
        gload_lds16(sm + (size_t)e * HD + ((pos ^ (e & 7)) << 3), &Bsm[r * 2048 + w * 512]);
    }
    // A stage: x f32 -> fp16, swizzled ds_write_b64
    #pragma unroll
    for (int p = 0; p < 8; ++p) {
        const int row = p * 16 + (t >> 4), f4c = t & 15;
        float4 u = *(const float4*)&xs[(size_t)(n0 + row) * CDIM + h * HD + f4c * 4];
        f16x4 q = {(_Float16)u.x, (_Float16)u.y, (_Float16)u.z, (_Float16)u.w};
        const int byte = row * 128 + (((f4c >> 1) ^ (row & 7)) << 4) + ((f4c & 1) << 3);
        *(f16x4*)((char*)Axt + byte) = q;
    }
    __syncthreads();

    f32x4 acc[2][4];
    #pragma unroll
    for (int m = 0; m < 2; ++m)
        #pragma unroll
        for (int g = 0; g < 4; ++g) acc[m][g] = (f32x4)(0.0f);

    #pragma unroll
    for (int ks = 0; ks < 2; ++ks) {
        f16x8 a[2], bb[4];
        #pragma unroll
        for (int m = 0; m < 2; ++m) {
            const int row = w * 32 + m * 16 + l15;
            a[m] = *(const f16x8*)((char*)Axt + row * 128 + (((ks * 4 + lk) ^ (row & 7)) << 4));
        }
        #pragma unroll
        for (int g = 0; g < 4; ++g) {
            const int e = g * 16 + l15;
            bb[g] = *(const f16x8*)((char*)Bsm + e * 128 + (((ks * 4 + lk) ^ (e & 7)) << 4));
        }
        #pragma unroll
        for (int m = 0; m < 2; ++m)
            #pragma unroll
            for (int g = 0; g < 4; ++g)
                acc[m][g] = __builtin_amdgcn_mfma_f32_16x16x32_f16(a[m], bb[g], acc[m][g], 0, 0, 0);
    }

    float* ob = out + (size_t)s * (8ULL * NTOK * CDIM) + (size_t)b * NTOK * CDIM;
    #pragma unroll
    for (int m = 0; m < 2; ++m)
        #pragma unroll
        for (int g = 0; g < 4; ++g) {
            const int row0 = n0 + w * 32 + m * 16 + lk * 4;
            const int col  = h * HD + g * 16 + l15;
            #pragma unroll
            for (int r = 0; r < 4; ++r)
                ob[(size_t)(row0 + r) * CDIM + col] = acc[m][g][r];
        }
}

// ---------------------------------------------------------------------------
extern "C" void kernel_launch(void* const* d_in, const int* in_sizes, int n_in,
                              void* d_out, int out_size, void* d_ws, size_t ws_size,
                              hipStream_t stream) {
    const float* x1   = (const float*)d_in[0];
    const float* x2   = (const float*)d_in[1];
    const float* Wkv1 = (const float*)d_in[2];
    const float* Wkv2 = (const float*)d_in[3];
    float* out = (float*)d_out;

    // Scratch layout inside d_out (128 MiB); every region is dead before
    // out_kernel overwrites d_out. smT (1 MiB) lives in d_ws.
    char* base = (char*)d_out;
    _Float16* XT   = (_Float16*)(base + 0);            // 64 MiB [sb][kb][c][64]
    _Float16* WVT  = (_Float16*)(base + 67108864);     // 1 MiB fp16 [s][j][k]
    _Float16* GPh  = (_Float16*)(base + 68157440);     // 16 MiB fp16 (2 partials)
    _Float16* TP   = (_Float16*)(base + 84934656);     // 16 MiB fp16 (2 partials)
    float*    CP   = (float*)(base + 101711872);       // 8 MiB f32 (4 partials)
    _Float16* SMT  = (_Float16*)d_ws;                  // 1 MiB

    hipLaunchKernelGGL(xpose_kernel, dim3(66, 4, 16), dim3(256), 0, stream,
                       x1, x2, Wkv1, Wkv2, XT, WVT);
    hipLaunchKernelGGL(gram_kernel, dim3(512), dim3(256), 0, stream, XT, GPh);
    hipLaunchKernelGGL(t_kernel, dim3(512), dim3(256), 0, stream, GPh, WVT, TP);
    hipLaunchKernelGGL(ctx_gemm_kernel, dim3(8, 16, 4), dim3(256), 0, stream,
                       TP, Wkv1, Wkv2, CP);
    hipLaunchKernelGGL(ctx_fin_kernel, dim3(8, 16), dim3(256), 0, stream, CP, SMT);
    hipLaunchKernelGGL(out_kernel, dim3(4096), dim3(256), 0, stream, x1, x2, SMT, out);
}

// Round 11
// 151.187 us; speedup vs baseline: 1.0313x; 1.0169x over previous
//
#include <hip/hip_runtime.h>
#include <hip/hip_bf16.h>

typedef __bf16   bf16x8 __attribute__((ext_vector_type(8)));
typedef _Float16 f16x8  __attribute__((ext_vector_type(8)));
typedef _Float16 f16x4  __attribute__((ext_vector_type(4)));
typedef float    f32x4  __attribute__((ext_vector_type(4)));

#define NTOK 4096
#define CDIM 512
#define HEADS 8
#define HD 64

__device__ __forceinline__ void gload_lds16(const void* g, void* l) {
    __builtin_amdgcn_global_load_lds((const __attribute__((address_space(1))) void*)g,
                                     (__attribute__((address_space(3))) void*)l, 16, 0, 0);
}

// ---------------------------------------------------------------------------
// P1 (merged): blocks x<64: x [sb][n][c] f32 -> XT [sb][kb][c][kk] fp16.
//              blocks x>=64: Wv transpose -> wvt fp16 [s][j][k].
// ---------------------------------------------------------------------------
__global__ __launch_bounds__(256, 4) void xpose_kernel(const float* __restrict__ x1,
                                                       const float* __restrict__ x2,
                                                       const float* __restrict__ Wkv1,
                                                       const float* __restrict__ Wkv2,
                                                       _Float16* __restrict__ xt,
                                                       _Float16* __restrict__ wvt) {
    const int t = threadIdx.x, w = t >> 6, l = t & 63;

    if (blockIdx.x >= 64) {
        // ---- wtrans role ----
        if (blockIdx.z >= 8) return;
        const int s = blockIdx.x - 64;
        const float* W = (s ? Wkv2 : Wkv1);
        const int k0 = blockIdx.z * 64;
        const int j = blockIdx.y * 256 + w * 64 + l;

        f16x8 vh[8];
        #pragma unroll
        for (int q = 0; q < 64; ++q) {
            float v = W[(size_t)(k0 + q) * (2 * CDIM) + CDIM + j];
            vh[q >> 3][q & 7] = (_Float16)v;
        }
        _Float16* dh = wvt + ((size_t)s * CDIM + j) * CDIM + k0;
        #pragma unroll
        for (int q = 0; q < 8; ++q)
            *(f16x8*)&dh[q * 8] = vh[q];
        return;
    }

    // ---- xpose role ----
    const int kb = blockIdx.x, cb = blockIdx.y, sb = blockIdx.z;
    const int s = sb >> 3, b = sb & 7;
    const float* xs = (s ? x2 : x1) + (size_t)b * NTOK * CDIM
                    + (size_t)kb * 64 * CDIM + cb * 256;

    __shared__ _Float16 lds[64 * 256];

    // Phase A: all 16 loads issued before any LDS write (keep MLP high).
    float4 v[16];
    #pragma unroll
    for (int i = 0; i < 16; ++i) {
        const int n = 4 * i + w;
        v[i] = *(const float4*)&xs[(size_t)n * CDIM + l * 4];
    }
    #pragma unroll
    for (int i = 0; i < 16; ++i) {
        const int n = 4 * i + w;
        f16x4 p = {(_Float16)v[i].x, (_Float16)v[i].y, (_Float16)v[i].z, (_Float16)v[i].w};
        *(f16x4*)&lds[n * 256 + ((l ^ (n >> 3)) << 2)] = p;
    }
    __syncthreads();

    // Phase B: per q-instr the wave's 64 stores are byte-contiguous (1 KiB).
    const int kk8 = (l & 7);
    _Float16* dst = xt + ((size_t)(sb * 64 + kb) * CDIM + cb * 256) * 64;
    #pragma unroll
    for (int q = 0; q < 8; ++q) {
        const int cw = 64 * w + 8 * q + (l >> 3);
        const int c4s = (cw >> 2) ^ kk8, c2 = cw & 3;
        const int base = (c4s << 2) + c2 + kk8 * 8 * 256;
        f16x8 o;
        #pragma unroll
        for (int j = 0; j < 8; ++j)
            o[j] = lds[base + j * 256];
        *(f16x8*)&dst[(size_t)cw * 64 + kk8 * 8] = o;
    }
}

// ---------------------------------------------------------------------------
// Gram: GPh[split][sb] = xt(k-half)^T xt(k-half), fp16 MFMA, fp16 output.
// 512 blocks (2/CU), 2-phase pipeline, counted vmcnt(8), setprio on MFMA.
// ---------------------------------------------------------------------------
__global__ __launch_bounds__(256) void gram_kernel(const _Float16* __restrict__ xt,
                                                   _Float16* __restrict__ GPh) {
    const int id = blockIdx.x;                  // 512
    const int vid = (id & 7) * 64 + (id >> 3);  // XCD-contiguous
    const int sb = vid >> 5, rest = vid & 31;
    const int split = rest >> 4, tile = rest & 15;
    const int I0 = (tile >> 2) * 128, J0 = (tile & 3) * 128;
    const _Float16* xb = xt + (size_t)sb * CDIM * NTOK;

    __shared__ _Float16 Ih[2][128 * 64];
    __shared__ _Float16 Jh[2][128 * 64];

    const int t = threadIdx.x, w = t >> 6, l = t & 63;
    const int wm = w >> 1, wn = w & 1, l15 = l & 15, lk = l >> 4;
    const int colr = w * 8 + (l >> 3), pos = l & 7;

    f32x4 acc[4][4];
    #pragma unroll
    for (int f = 0; f < 4; ++f)
        #pragma unroll
        for (int g = 0; g < 4; ++g) acc[f][g] = (f32x4)(0.0f);

    auto STAGE = [&](int bufi, int it) {
        const _Float16* kb = xb + (size_t)(split * 32 + it) * CDIM * 64;
        #pragma unroll
        for (int r = 0; r < 4; ++r) {
            const int colw = r * 32 + colr;
            const int swz = ((pos ^ (colw & 7)) << 3);
            gload_lds16(kb + (size_t)(I0 + colw) * 64 + swz, &Ih[bufi][r * 2048 + w * 512]);
            gload_lds16(kb + (size_t)(J0 + colw) * 64 + swz, &Jh[bufi][r * 2048 + w * 512]);
        }
    };

    STAGE(0, 0);
    for (int it = 0; it < 32; ++it) {
        const int cur = it & 1;
        if (it < 31) {
            STAGE(cur ^ 1, it + 1);
            asm volatile("s_waitcnt vmcnt(8)" ::: "memory");
        } else {
            asm volatile("s_waitcnt vmcnt(0)" ::: "memory");
        }
        __builtin_amdgcn_s_barrier();

        const _Float16* Ib = &Ih[cur][0];
        const _Float16* Jb = &Jh[cur][0];
        __builtin_amdgcn_s_setprio(1);
        #pragma unroll
        for (int ks = 0; ks < 2; ++ks) {
            f16x8 a[4], bb[4];
            #pragma unroll
            for (int f = 0; f < 4; ++f) {
                const int i = wm * 64 + f * 16 + l15;
                a[f] = *(const f16x8*)&Ib[i * 64 + ((ks * 4 + lk) ^ (i & 7)) * 8];
            }
            #pragma unroll
            for (int g = 0; g < 4; ++g) {
                const int j = wn * 64 + g * 16 + l15;
                bb[g] = *(const f16x8*)&Jb[j * 64 + ((ks * 4 + lk) ^ (j & 7)) * 8];
            }
            #pragma unroll
            for (int f = 0; f < 4; ++f)
                #pragma unroll
                for (int g = 0; g < 4; ++g)
                    acc[f][g] = __builtin_amdgcn_mfma_f32_16x16x32_f16(a[f], bb[g], acc[f][g], 0, 0, 0);
        }
        __builtin_amdgcn_s_setprio(0);
        __builtin_amdgcn_s_barrier();
    }

    _Float16* Gout = GPh + ((size_t)split * 16 + sb) * CDIM * CDIM;
    #pragma unroll
    for (int f = 0; f < 4; ++f)
        #pragma unroll
        for (int g = 0; g < 4; ++g) {
            const int row0 = I0 + wm * 64 + f * 16 + lk * 4;
            const int col  = J0 + wn * 64 + g * 16 + l15;
            #pragma unroll
            for (int r = 0; r < 4; ++r)
                Gout[(size_t)(row0 + r) * CDIM + col] = (_Float16)acc[f][g][r];
        }
}

// ---------------------------------------------------------------------------
// T-partials: TP[ks2][sb] = (GPh0+GPh1)(k-range) @ Wv, single fp16 MFMA.
// 512 blocks (2/CU), XCD-aligned with gram's writer so G reads hit local L2.
// ---------------------------------------------------------------------------
__global__ __launch_bounds__(256) void t_kernel(const _Float16* __restrict__ GPh,
                                                const _Float16* __restrict__ wvt,
                                                _Float16* __restrict__ TP) {
    const int id = blockIdx.x;                  // 512
    const int vid = (id & 7) * 64 + (id >> 3);  // same XCD map as gram
    const int sb = vid >> 5, rest = vid & 31;
    const int ks2 = rest >> 4, tile = rest & 15;
    const int s = sb >> 3;
    const int I0 = (tile >> 2) * 128, J0 = (tile & 3) * 128;
    const _Float16* G0 = GPh + (size_t)sb * CDIM * CDIM;
    const _Float16* G1 = GPh + ((size_t)16 + sb) * CDIM * CDIM;
    const _Float16* Bv = wvt + (size_t)s * CDIM * CDIM;

    __shared__ _Float16 Ah[128 * 64];
    __shared__ _Float16 Jh[128 * 64];

    const int t = threadIdx.x, w = t >> 6, l = t & 63;
    const int wm = w >> 1, wn = w & 1, l15 = l & 15, lk = l >> 4;
    const int colr = w * 8 + (l >> 3), pos = l & 7;

    f32x4 acc[4][4];
    #pragma unroll
    for (int f = 0; f < 4; ++f)
        #pragma unroll
        for (int g = 0; g < 4; ++g) acc[f][g] = (f32x4)(0.0f);

    for (int it = 0; it < 4; ++it) {
        const int k0 = ks2 * 256 + it * 64;
        __syncthreads();
        // B stage first: async gloads fly while A-stage does its work
        #pragma unroll
        for (int r = 0; r < 4; ++r) {
            const int col = r * 32 + colr;
            const int swz = ((pos ^ (col & 7)) << 3);
            gload_lds16(Bv + (size_t)(J0 + col) * CDIM + k0 + swz, &Jh[r * 2048 + w * 512]);
        }
        // A stage: sum the two fp16 Gram partials, store swizzled
        #pragma unroll
        for (int r = 0; r < 4; ++r) {
            const int i = r * 32 + (t >> 3), ch = t & 7;
            const size_t off = (size_t)(I0 + i) * CDIM + k0 + ch * 8;
            f16x8 a0 = *(const f16x8*)&G0[off];
            f16x8 a1 = *(const f16x8*)&G1[off];
            f16x8 sum = a0 + a1;
            *(f16x8*)&Ah[i * 64 + ((ch ^ (i & 7)) << 3)] = sum;
        }
        __syncthreads();
        __builtin_amdgcn_s_setprio(1);
        #pragma unroll
        for (int ks = 0; ks < 2; ++ks) {
            f16x8 a[4], bb[4];
            #pragma unroll
            for (int f = 0; f < 4; ++f) {
                const int i = wm * 64 + f * 16 + l15;
                a[f] = *(const f16x8*)&Ah[i * 64 + ((ks * 4 + lk) ^ (i & 7)) * 8];
            }
            #pragma unroll
            for (int g = 0; g < 4; ++g) {
                const int j = wn * 64 + g * 16 + l15;
                bb[g] = *(const f16x8*)&Jh[j * 64 + ((ks * 4 + lk) ^ (j & 7)) * 8];
            }
            #pragma unroll
            for (int f = 0; f < 4; ++f)
                #pragma unroll
                for (int g = 0; g < 4; ++g)
                    acc[f][g] = __builtin_amdgcn_mfma_f32_16x16x32_f16(a[f], bb[g], acc[f][g], 0, 0, 0);
        }
        __builtin_amdgcn_s_setprio(0);
    }

    _Float16* Tb = TP + ((size_t)ks2 * 16 + sb) * CDIM * CDIM;
    #pragma unroll
    for (int f = 0; f < 4; ++f)
        #pragma unroll
        for (int g = 0; g < 4; ++g) {
            const int row0 = I0 + wm * 64 + f * 16 + lk * 4;
            const int col  = J0 + wn * 64 + g * 16 + l15;
            #pragma unroll
            for (int r = 0; r < 4; ++r)
                Tb[(size_t)(row0 + r) * CDIM + col] = (_Float16)acc[f][g][r];
        }
}

// ---------------------------------------------------------------------------
// ctx GEMM, K-split by 4: CP[kq][sb][h] = partial Wk_h^T (TP0+TP1)_h
// ---------------------------------------------------------------------------
__global__ __launch_bounds__(256) void ctx_gemm_kernel(const _Float16* __restrict__ TP,
                                                       const float* __restrict__ Wkv1,
                                                       const float* __restrict__ Wkv2,
                                                       float* __restrict__ CP) {
    const int h = blockIdx.x, sb = blockIdx.y, kq = blockIdx.z;
    const int s = sb >> 3;
    const float* W  = (s == 0 ? Wkv1 : Wkv2);
    const _Float16* T0 = TP + (size_t)sb * CDIM * CDIM;
    const _Float16* T1 = TP + ((size_t)16 + sb) * CDIM * CDIM;

    __shared__ float Kt[64][65];
    __shared__ float Tt[64][65];

    const int t = threadIdx.x;
    const int td = t >> 4, te = t & 15;
    float acc[4][4] = {};

    for (int it = 0; it < 2; ++it) {
        const int kc = kq * 128 + it * 64;
        __syncthreads();
        for (int i = 0; i < 16; ++i) {
            const int idx = t + i * 256;
            const int r = idx >> 6, cc = idx & 63;
            Kt[r][cc] = W[(size_t)(kc + r) * (2 * CDIM) + h * HD + cc];
            Tt[r][cc] = (float)T0[(size_t)(kc + r) * CDIM + h * HD + cc]
                      + (float)T1[(size_t)(kc + r) * CDIM + h * HD + cc];
        }
        __syncthreads();
        for (int k = 0; k < 64; ++k) {
            float a[4], bb[4];
            #pragma unroll
            for (int i = 0; i < 4; ++i) a[i] = Kt[k][td * 4 + i];
            #pragma unroll
            for (int j = 0; j < 4; ++j) bb[j] = Tt[k][te * 4 + j];
            #pragma unroll
            for (int i = 0; i < 4; ++i)
                #pragma unroll
                for (int j = 0; j < 4; ++j) acc[i][j] += a[i] * bb[j];
        }
    }
    float* out = CP + (size_t)(((kq * 16 + sb) * HEADS) + h) * HD * HD;
    for (int i = 0; i < 4; ++i)
        for (int j = 0; j < 4; ++j)
            out[(size_t)(td * 4 + i) * HD + te * 4 + j] = acc[i][j];
}

// ---------------------------------------------------------------------------
// ctx finish: sum 4 partials, scale, softmax over d -> smT fp16 [sb][h][e][d]
// ---------------------------------------------------------------------------
__global__ __launch_bounds__(256) void ctx_fin_kernel(const float* __restrict__ CP,
                                                      _Float16* __restrict__ smT) {
    const int h = blockIdx.x, sb = blockIdx.y;

    __shared__ float ctxs[64][65];
    __shared__ float mred[64], sred[64];

    const int t = threadIdx.x;
    const float scale = 0.125f;
    #pragma unroll
    for (int i = 0; i < 4; ++i) {
        const int idx4 = t + i * 256;
        const int d = idx4 >> 4, e4 = idx4 & 15;
        f32x4 sum = (f32x4)(0.0f);
        #pragma unroll
        for (int kq = 0; kq < 4; ++kq) {
            const float* p = CP + (size_t)(((kq * 16 + sb) * HEADS) + h) * HD * HD;
            f32x4 v = *(const f32x4*)&p[d * HD + e4 * 4];
            sum += v;
        }
        *(f32x4*)&ctxs[d][e4 * 4] = sum * scale;
    }
    __syncthreads();
    if (t < 64) {
        float m = -1e30f;
        for (int d = 0; d < 64; ++d) m = fmaxf(m, ctxs[d][t]);
        float ssum = 0.f;
        for (int d = 0; d < 64; ++d) ssum += expf(ctxs[d][t] - m);
        mred[t] = m;
        sred[t] = 1.0f / ssum;
    }
    __syncthreads();
    _Float16* smout = smT + (size_t)(sb * HEADS + h) * HD * HD;   // [e][d]
    #pragma unroll
    for (int i = 0; i < 16; ++i) {
        const int idx = t + i * 256;
        const int e = idx >> 6, d = idx & 63;
        smout[e * HD + d] = (_Float16)(expf(ctxs[d][e] - mred[e]) * sred[e]);
    }
}

// ---------------------------------------------------------------------------
// out: out_s[n, h*64+e] = sum_d x_s[n, h*64+d] * sm[1-s][h][d][e], fp16 MFMA.
// If use_xt: A sourced from XT fp16 (64 MiB read, half of f32 x) -- only
// valid when XT does NOT alias d_out. Else: round-8 path reading x f32.
// ---------------------------------------------------------------------------
__global__ __launch_bounds__(256) void out_kernel(const float* __restrict__ x1,
                                                  const float* __restrict__ x2,
                                                  const _Float16* __restrict__ xt,
                                                  const int use_xt,
                                                  const _Float16* __restrict__ smT,
                                                  float* __restrict__ out) {
    const int id = blockIdx.x;                   // 4096
    const int vid = (id & 7) * 512 + (id >> 3);  // h-groups co-XCD
    const int h = vid & 7, nt = (vid >> 3) & 31, sb = vid >> 8;
    const int s = sb >> 3, b = sb & 7;
    const float* xs = (s ? x2 : x1) + (size_t)b * NTOK * CDIM;
    const _Float16* sm = smT + (size_t)((((1 - s) * 8 + b) * HEADS) + h) * HD * HD;
    const int n0 = nt * 128;

    __shared__ _Float16 Axt[128 * 64];   // [n][d] swizzled
    __shared__ _Float16 Bsm[64 * 64];    // [e][d] swizzled

    const int t = threadIdx.x, w = t >> 6, l = t & 63;
    const int l15 = l & 15, lk = l >> 4;

    // B stage via gl_lds (2 rounds)
    #pragma unroll
    for (int r = 0; r < 2; ++r) {
        const int e = r * 32 + w * 8 + (l >> 3), pos = l & 7;
        gload_lds16(sm + (size_t)e * HD + ((pos ^ (e & 7)) << 3), &Bsm[r * 2048 + w * 512]);
    }

    if (use_xt) {
        // A stage from XT [sb][kb][c][kk] fp16: coalesced b128 reads,
        // swizzled u16 LDS writes (chunk = (d>>3)^j since row&7 == j).
        const int kb  = t >> 7;            // 0..1  (n-block of 64)
        const int cc  = (t >> 1) & 63;     // d within head
        const int kk0 = (t & 1) * 32;
        const _Float16* src = xt + ((size_t)(sb * 64 + nt * 2 + kb) * CDIM + h * HD + cc) * 64 + kk0;
        f16x8 vv[4];
        #pragma unroll
        for (int i = 0; i < 4; ++i)
            vv[i] = *(const f16x8*)(src + 8 * i);
        const int chunk = ((cc >> 3) << 4);          // (d>>3) slot base
        #pragma unroll
        for (int i = 0; i < 4; ++i) {
            #pragma unroll
            for (int j = 0; j < 8; ++j) {
                const int row = kb * 64 + kk0 + 8 * i + j;   // row&7 == j
                const int byte = row * 128 + (chunk ^ (j << 4)) + (cc & 7) * 2;
                *(_Float16*)((char*)Axt + byte) = vv[i][j];
            }
        }
    } else {
        // A stage: x f32 -> fp16, swizzled ds_write_b64 (round-8 path)
        #pragma unroll
        for (int p = 0; p < 8; ++p) {
            const int row = p * 16 + (t >> 4), f4c = t & 15;
            float4 u = *(const float4*)&xs[(size_t)(n0 + row) * CDIM + h * HD + f4c * 4];
            f16x4 q = {(_Float16)u.x, (_Float16)u.y, (_Float16)u.z, (_Float16)u.w};
            const int byte = row * 128 + (((f4c >> 1) ^ (row & 7)) << 4) + ((f4c & 1) << 3);
            *(f16x4*)((char*)Axt + byte) = q;
        }
    }
    __syncthreads();

    f32x4 acc[2][4];
    #pragma unroll
    for (int m = 0; m < 2; ++m)
        #pragma unroll
        for (int g = 0; g < 4; ++g) acc[m][g] = (f32x4)(0.0f);

    #pragma unroll
    for (int ks = 0; ks < 2; ++ks) {
        f16x8 a[2], bb[4];
        #pragma unroll
        for (int m = 0; m < 2; ++m) {
            const int row = w * 32 + m * 16 + l15;
            a[m] = *(const f16x8*)((char*)Axt + row * 128 + (((ks * 4 + lk) ^ (row & 7)) << 4));
        }
        #pragma unroll
        for (int g = 0; g < 4; ++g) {
            const int e = g * 16 + l15;
            bb[g] = *(const f16x8*)((char*)Bsm + e * 128 + (((ks * 4 + lk) ^ (e & 7)) << 4));
        }
        #pragma unroll
        for (int m = 0; m < 2; ++m)
            #pragma unroll
            for (int g = 0; g < 4; ++g)
                acc[m][g] = __builtin_amdgcn_mfma_f32_16x16x32_f16(a[m], bb[g], acc[m][g], 0, 0, 0);
    }

    float* ob = out + (size_t)s * (8ULL * NTOK * CDIM) + (size_t)b * NTOK * CDIM;
    #pragma unroll
    for (int m = 0; m < 2; ++m)
        #pragma unroll
        for (int g = 0; g < 4; ++g) {
            const int row0 = n0 + w * 32 + m * 16 + lk * 4;
            const int col  = h * HD + g * 16 + l15;
            #pragma unroll
            for (int r = 0; r < 4; ++r)
                ob[(size_t)(row0 + r) * CDIM + col] = acc[m][g][r];
        }
}

// ---------------------------------------------------------------------------
extern "C" void kernel_launch(void* const* d_in, const int* in_sizes, int n_in,
                              void* d_out, int out_size, void* d_ws, size_t ws_size,
                              hipStream_t stream) {
    const float* x1   = (const float*)d_in[0];
    const float* x2   = (const float*)d_in[1];
    const float* Wkv1 = (const float*)d_in[2];
    const float* Wkv2 = (const float*)d_in[3];
    float* out = (float*)d_out;

    // Scratch sizes: XT 64Mi, WVT 1Mi, GPh 16Mi, TP 16Mi, CP 8Mi, SMT 1Mi.
    // Preferred: all in d_ws (no aliasing) -> out_kernel may read XT (halves
    // its read traffic). Fallback (small ws): round-8 layout inside d_out,
    // out_kernel reads x f32 (XT is dead only in that aliased layout).
    const size_t NEED = 111149056;  // 106 MiB
    _Float16 *XT, *WVT, *GPh, *TP, *SMT;
    float* CP;
    int use_xt;
    if (ws_size >= NEED) {
        char* base = (char*)d_ws;
        XT  = (_Float16*)(base + 0);
        WVT = (_Float16*)(base + 67108864);
        GPh = (_Float16*)(base + 68157440);
        TP  = (_Float16*)(base + 84934656);
        CP  = (float*)  (base + 101711872);
        SMT = (_Float16*)(base + 110100480);
        use_xt = 1;
    } else {
        char* base = (char*)d_out;
        XT  = (_Float16*)(base + 0);
        WVT = (_Float16*)(base + 67108864);
        GPh = (_Float16*)(base + 68157440);
        TP  = (_Float16*)(base + 84934656);
        CP  = (float*)  (base + 101711872);
        SMT = (_Float16*)d_ws;
        use_xt = 0;
    }

    hipLaunchKernelGGL(xpose_kernel, dim3(66, 2, 16), dim3(256), 0, stream,
                       x1, x2, Wkv1, Wkv2, XT, WVT);
    hipLaunchKernelGGL(gram_kernel, dim3(512), dim3(256), 0, stream, XT, GPh);
    hipLaunchKernelGGL(t_kernel, dim3(512), dim3(256), 0, stream, GPh, WVT, TP);
    hipLaunchKernelGGL(ctx_gemm_kernel, dim3(8, 16, 4), dim3(256), 0, stream,
                       TP, Wkv1, Wkv2, CP);
    hipLaunchKernelGGL(ctx_fin_kernel, dim3(8, 16), dim3(256), 0, stream, CP, SMT);
    hipLaunchKernelGGL(out_kernel, dim3(4096), dim3(256), 0, stream,
                       x1, x2, XT, use_xt, SMT, out);
}

// Round 12
// 145.174 us; speedup vs baseline: 1.0741x; 1.0414x over previous
//
#include <hip/hip_runtime.h>
#include <hip/hip_bf16.h>

typedef __bf16   bf16x8 __attribute__((ext_vector_type(8)));
typedef _Float16 f16x8  __attribute__((ext_vector_type(8)));
typedef _Float16 f16x4  __attribute__((ext_vector_type(4)));
typedef float    f32x4  __attribute__((ext_vector_type(4)));

#define NTOK 4096
#define CDIM 512
#define HEADS 8
#define HD 64

__device__ __forceinline__ void gload_lds16(const void* g, void* l) {
    __builtin_amdgcn_global_load_lds((const __attribute__((address_space(1))) void*)g,
                                     (__attribute__((address_space(3))) void*)l, 16, 0, 0);
}

// ---------------------------------------------------------------------------
// P1 (merged): blocks x<64: x [sb][n][c] f32 -> XT [sb][kb][c][kk] fp16.
//              blocks x>=64: Wv transpose -> wvt fp16 [s][j][k].
// ---------------------------------------------------------------------------
__global__ __launch_bounds__(256, 4) void xpose_kernel(const float* __restrict__ x1,
                                                       const float* __restrict__ x2,
                                                       const float* __restrict__ Wkv1,
                                                       const float* __restrict__ Wkv2,
                                                       _Float16* __restrict__ xt,
                                                       _Float16* __restrict__ wvt) {
    const int t = threadIdx.x, w = t >> 6, l = t & 63;

    if (blockIdx.x >= 64) {
        // ---- wtrans role ----
        if (blockIdx.z >= 8) return;
        const int s = blockIdx.x - 64;
        const float* W = (s ? Wkv2 : Wkv1);
        const int k0 = blockIdx.z * 64;
        const int j = blockIdx.y * 256 + w * 64 + l;

        f16x8 vh[8];
        #pragma unroll
        for (int q = 0; q < 64; ++q) {
            float v = W[(size_t)(k0 + q) * (2 * CDIM) + CDIM + j];
            vh[q >> 3][q & 7] = (_Float16)v;
        }
        _Float16* dh = wvt + ((size_t)s * CDIM + j) * CDIM + k0;
        #pragma unroll
        for (int q = 0; q < 8; ++q)
            *(f16x8*)&dh[q * 8] = vh[q];
        return;
    }

    // ---- xpose role ----
    const int kb = blockIdx.x, cb = blockIdx.y, sb = blockIdx.z;
    const int s = sb >> 3, b = sb & 7;
    const float* xs = (s ? x2 : x1) + (size_t)b * NTOK * CDIM
                    + (size_t)kb * 64 * CDIM + cb * 256;

    __shared__ _Float16 lds[64 * 256];

    // Phase A: all 16 loads issued before any LDS write (keep MLP high).
    float4 v[16];
    #pragma unroll
    for (int i = 0; i < 16; ++i) {
        const int n = 4 * i + w;
        v[i] = *(const float4*)&xs[(size_t)n * CDIM + l * 4];
    }
    #pragma unroll
    for (int i = 0; i < 16; ++i) {
        const int n = 4 * i + w;
        f16x4 p = {(_Float16)v[i].x, (_Float16)v[i].y, (_Float16)v[i].z, (_Float16)v[i].w};
        *(f16x4*)&lds[n * 256 + ((l ^ (n >> 3)) << 2)] = p;
    }
    __syncthreads();

    // Phase B: per q-instr the wave's 64 stores are byte-contiguous (1 KiB).
    const int kk8 = (l & 7);
    _Float16* dst = xt + ((size_t)(sb * 64 + kb) * CDIM + cb * 256) * 64;
    #pragma unroll
    for (int q = 0; q < 8; ++q) {
        const int cw = 64 * w + 8 * q + (l >> 3);
        const int c4s = (cw >> 2) ^ kk8, c2 = cw & 3;
        const int base = (c4s << 2) + c2 + kk8 * 8 * 256;
        f16x8 o;
        #pragma unroll
        for (int j = 0; j < 8; ++j)
            o[j] = lds[base + j * 256];
        *(f16x8*)&dst[(size_t)cw * 64 + kk8 * 8] = o;
    }
}

// ---------------------------------------------------------------------------
// Gram (symmetric, K-split 3): GPh[split(3)][sb] = xt(k-range)^T xt(k-range).
// Only the 10 upper tiles (ti<=tj) are computed; off-diag tiles are mirrored
// with contiguous f16x4 stores. 480 blocks (all co-resident, <=2/CU) =>
// makespan 1.33W vs 2W. Branchless ti/tj decode (no scratch arrays).
// 2-phase pipeline, counted vmcnt(8), setprio on MFMA.
// ---------------------------------------------------------------------------
__global__ __launch_bounds__(256) void gram_kernel(const _Float16* __restrict__ xt,
                                                   _Float16* __restrict__ GPh) {
    const int id = blockIdx.x;                  // 480
    const int vid = (id & 7) * 60 + (id >> 3);  // XCD-bijective: sb {2g,2g+1} on XCD g
    const int sb = vid / 30, r30 = vid % 30;
    const int split = r30 / 10, tidx = r30 % 10;
    const int ti = (tidx >= 4) + (tidx >= 7) + (tidx >= 9);
    const int tj = tidx + ti - ((ti == 0) ? 0 : (ti == 1) ? 4 : (ti == 2) ? 7 : 9);
    const int I0 = ti * 128, J0 = tj * 128;
    const int kbeg = (split * 64) / 3, kend = ((split + 1) * 64) / 3;  // 21/21/22 iters
    const _Float16* xb = xt + (size_t)sb * CDIM * NTOK;

    __shared__ _Float16 Ih[2][128 * 64];
    __shared__ _Float16 Jh[2][128 * 64];

    const int t = threadIdx.x, w = t >> 6, l = t & 63;
    const int wm = w >> 1, wn = w & 1, l15 = l & 15, lk = l >> 4;
    const int colr = w * 8 + (l >> 3), pos = l & 7;

    f32x4 acc[4][4];
    #pragma unroll
    for (int f = 0; f < 4; ++f)
        #pragma unroll
        for (int g = 0; g < 4; ++g) acc[f][g] = (f32x4)(0.0f);

    auto STAGE = [&](int bufi, int it) {
        const _Float16* kb = xb + (size_t)it * CDIM * 64;
        #pragma unroll
        for (int r = 0; r < 4; ++r) {
            const int colw = r * 32 + colr;
            const int swz = ((pos ^ (colw & 7)) << 3);
            gload_lds16(kb + (size_t)(I0 + colw) * 64 + swz, &Ih[bufi][r * 2048 + w * 512]);
            gload_lds16(kb + (size_t)(J0 + colw) * 64 + swz, &Jh[bufi][r * 2048 + w * 512]);
        }
    };

    STAGE(0, kbeg);
    for (int it = kbeg; it < kend; ++it) {
        const int cur = (it - kbeg) & 1;
        if (it < kend - 1) {
            STAGE(cur ^ 1, it + 1);
            asm volatile("s_waitcnt vmcnt(8)" ::: "memory");
        } else {
            asm volatile("s_waitcnt vmcnt(0)" ::: "memory");
        }
        __builtin_amdgcn_s_barrier();

        const _Float16* Ib = &Ih[cur][0];
        const _Float16* Jb = &Jh[cur][0];
        __builtin_amdgcn_s_setprio(1);
        #pragma unroll
        for (int ks = 0; ks < 2; ++ks) {
            f16x8 a[4], bb[4];
            #pragma unroll
            for (int f = 0; f < 4; ++f) {
                const int i = wm * 64 + f * 16 + l15;
                a[f] = *(const f16x8*)&Ib[i * 64 + ((ks * 4 + lk) ^ (i & 7)) * 8];
            }
            #pragma unroll
            for (int g = 0; g < 4; ++g) {
                const int j = wn * 64 + g * 16 + l15;
                bb[g] = *(const f16x8*)&Jb[j * 64 + ((ks * 4 + lk) ^ (j & 7)) * 8];
            }
            #pragma unroll
            for (int f = 0; f < 4; ++f)
                #pragma unroll
                for (int g = 0; g < 4; ++g)
                    acc[f][g] = __builtin_amdgcn_mfma_f32_16x16x32_f16(a[f], bb[g], acc[f][g], 0, 0, 0);
        }
        __builtin_amdgcn_s_setprio(0);
        __builtin_amdgcn_s_barrier();
    }

    _Float16* Gout = GPh + ((size_t)split * 16 + sb) * CDIM * CDIM;
    #pragma unroll
    for (int f = 0; f < 4; ++f)
        #pragma unroll
        for (int g = 0; g < 4; ++g) {
            const int row0 = I0 + wm * 64 + f * 16 + lk * 4;
            const int col  = J0 + wn * 64 + g * 16 + l15;
            #pragma unroll
            for (int r = 0; r < 4; ++r)
                Gout[(size_t)(row0 + r) * CDIM + col] = (_Float16)acc[f][g][r];
            if (ti != tj) {
                // mirror: 4 consecutive rows at fixed col -> contiguous f16x4
                f16x4 m = {(_Float16)acc[f][g][0], (_Float16)acc[f][g][1],
                           (_Float16)acc[f][g][2], (_Float16)acc[f][g][3]};
                *(f16x4*)&Gout[(size_t)col * CDIM + row0] = m;
            }
        }
}

// ---------------------------------------------------------------------------
// T-partials: TP[ks2][sb] = (GPh0+GPh1+GPh2)(k-range) @ Wv, single fp16 MFMA.
// 512 blocks (2/CU), XCD-aligned with gram's writer so G reads hit local L2.
// ---------------------------------------------------------------------------
__global__ __launch_bounds__(256) void t_kernel(const _Float16* __restrict__ GPh,
                                                const _Float16* __restrict__ wvt,
                                                _Float16* __restrict__ TP) {
    const int id = blockIdx.x;                  // 512
    const int vid = (id & 7) * 64 + (id >> 3);  // same XCD map as gram
    const int sb = vid >> 5, rest = vid & 31;
    const int ks2 = rest >> 4, tile = rest & 15;
    const int s = sb >> 3;
    const int I0 = (tile >> 2) * 128, J0 = (tile & 3) * 128;
    const _Float16* G0 = GPh + (size_t)sb * CDIM * CDIM;
    const _Float16* G1 = GPh + ((size_t)16 + sb) * CDIM * CDIM;
    const _Float16* G2 = GPh + ((size_t)32 + sb) * CDIM * CDIM;
    const _Float16* Bv = wvt + (size_t)s * CDIM * CDIM;

    __shared__ _Float16 Ah[128 * 64];
    __shared__ _Float16 Jh[128 * 64];

    const int t = threadIdx.x, w = t >> 6, l = t & 63;
    const int wm = w >> 1, wn = w & 1, l15 = l & 15, lk = l >> 4;
    const int colr = w * 8 + (l >> 3), pos = l & 7;

    f32x4 acc[4][4];
    #pragma unroll
    for (int f = 0; f < 4; ++f)
        #pragma unroll
        for (int g = 0; g < 4; ++g) acc[f][g] = (f32x4)(0.0f);

    for (int it = 0; it < 4; ++it) {
        const int k0 = ks2 * 256 + it * 64;
        __syncthreads();
        // B stage first: async gloads fly while A-stage does its work
        #pragma unroll
        for (int r = 0; r < 4; ++r) {
            const int col = r * 32 + colr;
            const int swz = ((pos ^ (col & 7)) << 3);
            gload_lds16(Bv + (size_t)(J0 + col) * CDIM + k0 + swz, &Jh[r * 2048 + w * 512]);
        }
        // A stage: sum the three fp16 Gram partials, store swizzled
        #pragma unroll
        for (int r = 0; r < 4; ++r) {
            const int i = r * 32 + (t >> 3), ch = t & 7;
            const size_t off = (size_t)(I0 + i) * CDIM + k0 + ch * 8;
            f16x8 a0 = *(const f16x8*)&G0[off];
            f16x8 a1 = *(const f16x8*)&G1[off];
            f16x8 a2 = *(const f16x8*)&G2[off];
            f16x8 sum = (a0 + a1) + a2;
            *(f16x8*)&Ah[i * 64 + ((ch ^ (i & 7)) << 3)] = sum;
        }
        __syncthreads();
        __builtin_amdgcn_s_setprio(1);
        #pragma unroll
        for (int ks = 0; ks < 2; ++ks) {
            f16x8 a[4], bb[4];
            #pragma unroll
            for (int f = 0; f < 4; ++f) {
                const int i = wm * 64 + f * 16 + l15;
                a[f] = *(const f16x8*)&Ah[i * 64 + ((ks * 4 + lk) ^ (i & 7)) * 8];
            }
            #pragma unroll
            for (int g = 0; g < 4; ++g) {
                const int j = wn * 64 + g * 16 + l15;
                bb[g] = *(const f16x8*)&Jh[j * 64 + ((ks * 4 + lk) ^ (j & 7)) * 8];
            }
            #pragma unroll
            for (int f = 0; f < 4; ++f)
                #pragma unroll
                for (int g = 0; g < 4; ++g)
                    acc[f][g] = __builtin_amdgcn_mfma_f32_16x16x32_f16(a[f], bb[g], acc[f][g], 0, 0, 0);
        }
        __builtin_amdgcn_s_setprio(0);
    }

    _Float16* Tb = TP + ((size_t)ks2 * 16 + sb) * CDIM * CDIM;
    #pragma unroll
    for (int f = 0; f < 4; ++f)
        #pragma unroll
        for (int g = 0; g < 4; ++g) {
            const int row0 = I0 + wm * 64 + f * 16 + lk * 4;
            const int col  = J0 + wn * 64 + g * 16 + l15;
            #pragma unroll
            for (int r = 0; r < 4; ++r)
                Tb[(size_t)(row0 + r) * CDIM + col] = (_Float16)acc[f][g][r];
        }
}

// ---------------------------------------------------------------------------
// ctx GEMM, K-split by 4: CP[kq][sb][h] = partial Wk_h^T (TP0+TP1)_h
// ---------------------------------------------------------------------------
__global__ __launch_bounds__(256) void ctx_gemm_kernel(const _Float16* __restrict__ TP,
                                                       const float* __restrict__ Wkv1,
                                                       const float* __restrict__ Wkv2,
                                                       float* __restrict__ CP) {
    const int h = blockIdx.x, sb = blockIdx.y, kq = blockIdx.z;
    const int s = sb >> 3;
    const float* W  = (s == 0 ? Wkv1 : Wkv2);
    const _Float16* T0 = TP + (size_t)sb * CDIM * CDIM;
    const _Float16* T1 = TP + ((size_t)16 + sb) * CDIM * CDIM;

    __shared__ float Kt[64][65];
    __shared__ float Tt[64][65];

    const int t = threadIdx.x;
    const int td = t >> 4, te = t & 15;
    float acc[4][4] = {};

    for (int it = 0; it < 2; ++it) {
        const int kc = kq * 128 + it * 64;
        __syncthreads();
        for (int i = 0; i < 16; ++i) {
            const int idx = t + i * 256;
            const int r = idx >> 6, cc = idx & 63;
            Kt[r][cc] = W[(size_t)(kc + r) * (2 * CDIM) + h * HD + cc];
            Tt[r][cc] = (float)T0[(size_t)(kc + r) * CDIM + h * HD + cc]
                      + (float)T1[(size_t)(kc + r) * CDIM + h * HD + cc];
        }
        __syncthreads();
        for (int k = 0; k < 64; ++k) {
            float a[4], bb[4];
            #pragma unroll
            for (int i = 0; i < 4; ++i) a[i] = Kt[k][td * 4 + i];
            #pragma unroll
            for (int j = 0; j < 4; ++j) bb[j] = Tt[k][te * 4 + j];
            #pragma unroll
            for (int i = 0; i < 4; ++i)
                #pragma unroll
                for (int j = 0; j < 4; ++j) acc[i][j] += a[i] * bb[j];
        }
    }
    float* out = CP + (size_t)(((kq * 16 + sb) * HEADS) + h) * HD * HD;
    for (int i = 0; i < 4; ++i)
        for (int j = 0; j < 4; ++j)
            out[(size_t)(td * 4 + i) * HD + te * 4 + j] = acc[i][j];
}

// ---------------------------------------------------------------------------
// ctx finish: sum 4 partials, scale, softmax over d -> smT fp16 [sb][h][e][d]
// ---------------------------------------------------------------------------
__global__ __launch_bounds__(256) void ctx_fin_kernel(const float* __restrict__ CP,
                                                      _Float16* __restrict__ smT) {
    const int h = blockIdx.x, sb = blockIdx.y;

    __shared__ float ctxs[64][65];
    __shared__ float mred[64], sred[64];

    const int t = threadIdx.x;
    const float scale = 0.125f;
    #pragma unroll
    for (int i = 0; i < 4; ++i) {
        const int idx4 = t + i * 256;
        const int d = idx4 >> 4, e4 = idx4 & 15;
        f32x4 sum = (f32x4)(0.0f);
        #pragma unroll
        for (int kq = 0; kq < 4; ++kq) {
            const float* p = CP + (size_t)(((kq * 16 + sb) * HEADS) + h) * HD * HD;
            f32x4 v = *(const f32x4*)&p[d * HD + e4 * 4];
            sum += v;
        }
        *(f32x4*)&ctxs[d][e4 * 4] = sum * scale;
    }
    __syncthreads();
    if (t < 64) {
        float m = -1e30f;
        for (int d = 0; d < 64; ++d) m = fmaxf(m, ctxs[d][t]);
        float ssum = 0.f;
        for (int d = 0; d < 64; ++d) ssum += expf(ctxs[d][t] - m);
        mred[t] = m;
        sred[t] = 1.0f / ssum;
    }
    __syncthreads();
    _Float16* smout = smT + (size_t)(sb * HEADS + h) * HD * HD;   // [e][d]
    #pragma unroll
    for (int i = 0; i < 16; ++i) {
        const int idx = t + i * 256;
        const int e = idx >> 6, d = idx & 63;
        smout[e * HD + d] = (_Float16)(expf(ctxs[d][e] - mred[e]) * sred[e]);
    }
}

// ---------------------------------------------------------------------------
// out: out_s[n, h*64+e] = sum_d x_s[n, h*64+d] * sm[1-s][h][d][e], fp16 MFMA.
// If use_xt: A sourced from XT fp16 (64 MiB read, half of f32 x) -- only
// valid when XT does NOT alias d_out. Else: round-8 path reading x f32.
// ---------------------------------------------------------------------------
__global__ __launch_bounds__(256) void out_kernel(const float* __restrict__ x1,
                                                  const float* __restrict__ x2,
                                                  const _Float16* __restrict__ xt,
                                                  const int use_xt,
                                                  const _Float16* __restrict__ smT,
                                                  float* __restrict__ out) {
    const int id = blockIdx.x;                   // 4096
    const int vid = (id & 7) * 512 + (id >> 3);  // h-groups co-XCD
    const int h = vid & 7, nt = (vid >> 3) & 31, sb = vid >> 8;
    const int s = sb >> 3, b = sb & 7;
    const float* xs = (s ? x2 : x1) + (size_t)b * NTOK * CDIM;
    const _Float16* sm = smT + (size_t)((((1 - s) * 8 + b) * HEADS) + h) * HD * HD;
    const int n0 = nt * 128;

    __shared__ _Float16 Axt[128 * 64];   // [n][d] swizzled
    __shared__ _Float16 Bsm[64 * 64];    // [e][d] swizzled

    const int t = threadIdx.x, w = t >> 6, l = t & 63;
    const int l15 = l & 15, lk = l >> 4;

    // B stage via gl_lds (2 rounds)
    #pragma unroll
    for (int r = 0; r < 2; ++r) {
        const int e = r * 32 + w * 8 + (l >> 3), pos = l & 7;
        gload_lds16(sm + (size_t)e * HD + ((pos ^ (e & 7)) << 3), &Bsm[r * 2048 + w * 512]);
    }

    if (use_xt) {
        const int kb  = t >> 7;            // 0..1  (n-block of 64)
        const int cc  = (t >> 1) & 63;     // d within head
        const int kk0 = (t & 1) * 32;
        const _Float16* src = xt + ((size_t)(sb * 64 + nt * 2 + kb) * CDIM + h * HD + cc) * 64 + kk0;
        f16x8 vv[4];
        #pragma unroll
        for (int i = 0; i < 4; ++i)
            vv[i] = *(const f16x8*)(src + 8 * i);
        const int chunk = ((cc >> 3) << 4);
        #pragma unroll
        for (int i = 0; i < 4; ++i) {
            #pragma unroll
            for (int j = 0; j < 8; ++j) {
                const int row = kb * 64 + kk0 + 8 * i + j;   // row&7 == j
                const int byte = row * 128 + (chunk ^ (j << 4)) + (cc & 7) * 2;
                *(_Float16*)((char*)Axt + byte) = vv[i][j];
            }
        }
    } else {
        #pragma unroll
        for (int p = 0; p < 8; ++p) {
            const int row = p * 16 + (t >> 4), f4c = t & 15;
            float4 u = *(const float4*)&xs[(size_t)(n0 + row) * CDIM + h * HD + f4c * 4];
            f16x4 q = {(_Float16)u.x, (_Float16)u.y, (_Float16)u.z, (_Float16)u.w};
            const int byte = row * 128 + (((f4c >> 1) ^ (row & 7)) << 4) + ((f4c & 1) << 3);
            *(f16x4*)((char*)Axt + byte) = q;
        }
    }
    __syncthreads();

    f32x4 acc[2][4];
    #pragma unroll
    for (int m = 0; m < 2; ++m)
        #pragma unroll
        for (int g = 0; g < 4; ++g) acc[m][g] = (f32x4)(0.0f);

    #pragma unroll
    for (int ks = 0; ks < 2; ++ks) {
        f16x8 a[2], bb[4];
        #pragma unroll
        for (int m = 0; m < 2; ++m) {
            const int row = w * 32 + m * 16 + l15;
            a[m] = *(const f16x8*)((char*)Axt + row * 128 + (((ks * 4 + lk) ^ (row & 7)) << 4));
        }
        #pragma unroll
        for (int g = 0; g < 4; ++g) {
            const int e = g * 16 + l15;
            bb[g] = *(const f16x8*)((char*)Bsm + e * 128 + (((ks * 4 + lk) ^ (e & 7)) << 4));
        }
        #pragma unroll
        for (int m = 0; m < 2; ++m)
            #pragma unroll
            for (int g = 0; g < 4; ++g)
                acc[m][g] = __builtin_amdgcn_mfma_f32_16x16x32_f16(a[m], bb[g], acc[m][g], 0, 0, 0);
    }

    float* ob = out + (size_t)s * (8ULL * NTOK * CDIM) + (size_t)b * NTOK * CDIM;
    #pragma unroll
    for (int m = 0; m < 2; ++m)
        #pragma unroll
        for (int g = 0; g < 4; ++g) {
            const int row0 = n0 + w * 32 + m * 16 + lk * 4;
            const int col  = h * HD + g * 16 + l15;
            #pragma unroll
            for (int r = 0; r < 4; ++r)
                ob[(size_t)(row0 + r) * CDIM + col] = acc[m][g][r];
        }
}

// ---------------------------------------------------------------------------
extern "C" void kernel_launch(void* const* d_in, const int* in_sizes, int n_in,
                              void* d_out, int out_size, void* d_ws, size_t ws_size,
                              hipStream_t stream) {
    const float* x1   = (const float*)d_in[0];
    const float* x2   = (const float*)d_in[1];
    const float* Wkv1 = (const float*)d_in[2];
    const float* Wkv2 = (const float*)d_in[3];
    float* out = (float*)d_out;

    // Scratch: XT 64Mi, WVT 1Mi, GPh 24Mi (3 partials), TP 16Mi, CP 8Mi, SMT 1Mi.
    // Preferred: all in d_ws (no aliasing; out_kernel reads XT). Fallback:
    // inside d_out (all regions dead before out_kernel), out reads x f32.
    const size_t NEED = 120586240;  // ~115 MiB
    _Float16 *XT, *WVT, *GPh, *TP, *SMT;
    float* CP;
    int use_xt;
    if (ws_size >= NEED) {
        char* base = (char*)d_ws;
        XT  = (_Float16*)(base + 0);
        WVT = (_Float16*)(base + 67108864);
        GPh = (_Float16*)(base + 68157440);
        TP  = (_Float16*)(base + 93323264);
        CP  = (float*)  (base + 110100480);
        SMT = (_Float16*)(base + 118489088);
        use_xt = 1;
    } else {
        char* base = (char*)d_out;
        XT  = (_Float16*)(base + 0);
        WVT = (_Float16*)(base + 67108864);
        GPh = (_Float16*)(base + 68157440);
        TP  = (_Float16*)(base + 93323264);
        CP  = (float*)  (base + 110100480);
        SMT = (_Float16*)d_ws;
        use_xt = 0;
    }

    hipLaunchKernelGGL(xpose_kernel, dim3(66, 2, 16), dim3(256), 0, stream,
                       x1, x2, Wkv1, Wkv2, XT, WVT);
    hipLaunchKernelGGL(gram_kernel, dim3(480), dim3(256), 0, stream, XT, GPh);
    hipLaunchKernelGGL(t_kernel, dim3(512), dim3(256), 0, stream, GPh, WVT, TP);
    hipLaunchKernelGGL(ctx_gemm_kernel, dim3(8, 16, 4), dim3(256), 0, stream,
                       TP, Wkv1, Wkv2, CP);
    hipLaunchKernelGGL(ctx_fin_kernel, dim3(8, 16), dim3(256), 0, stream, CP, SMT);
    hipLaunchKernelGGL(out_kernel, dim3(4096), dim3(256), 0, stream,
                       x1, x2, XT, use_xt, SMT, out);
}

// Round 13
// 144.883 us; speedup vs baseline: 1.0762x; 1.0020x over previous
//
#include <hip/hip_runtime.h>
#include <hip/hip_bf16.h>

typedef __bf16   bf16x8 __attribute__((ext_vector_type(8)));
typedef _Float16 f16x8  __attribute__((ext_vector_type(8)));
typedef _Float16 f16x4  __attribute__((ext_vector_type(4)));
typedef float    f32x4  __attribute__((ext_vector_type(4)));

#define NTOK 4096
#define CDIM 512
#define HEADS 8
#define HD 64

__device__ __forceinline__ void gload_lds16(const void* g, void* l) {
    __builtin_amdgcn_global_load_lds((const __attribute__((address_space(1))) void*)g,
                                     (__attribute__((address_space(3))) void*)l, 16, 0, 0);
}

// ---------------------------------------------------------------------------
// P1 (merged): blocks x<64: x [sb][n][c] f32 -> XT [sb][kb][c][kk] fp16.
//              blocks x>=64: Wv transpose -> wvt fp16 [s][j][k].
// ---------------------------------------------------------------------------
__global__ __launch_bounds__(256, 4) void xpose_kernel(const float* __restrict__ x1,
                                                       const float* __restrict__ x2,
                                                       const float* __restrict__ Wkv1,
                                                       const float* __restrict__ Wkv2,
                                                       _Float16* __restrict__ xt,
                                                       _Float16* __restrict__ wvt) {
    const int t = threadIdx.x, w = t >> 6, l = t & 63;

    if (blockIdx.x >= 64) {
        // ---- wtrans role ----
        if (blockIdx.z >= 8) return;
        const int s = blockIdx.x - 64;
        const float* W = (s ? Wkv2 : Wkv1);
        const int k0 = blockIdx.z * 64;
        const int j = blockIdx.y * 256 + w * 64 + l;

        f16x8 vh[8];
        #pragma unroll
        for (int q = 0; q < 64; ++q) {
            float v = W[(size_t)(k0 + q) * (2 * CDIM) + CDIM + j];
            vh[q >> 3][q & 7] = (_Float16)v;
        }
        _Float16* dh = wvt + ((size_t)s * CDIM + j) * CDIM + k0;
        #pragma unroll
        for (int q = 0; q < 8; ++q)
            *(f16x8*)&dh[q * 8] = vh[q];
        return;
    }

    // ---- xpose role ----
    const int kb = blockIdx.x, cb = blockIdx.y, sb = blockIdx.z;
    const int s = sb >> 3, b = sb & 7;
    const float* xs = (s ? x2 : x1) + (size_t)b * NTOK * CDIM
                    + (size_t)kb * 64 * CDIM + cb * 256;

    __shared__ _Float16 lds[64 * 256];

    // Phase A: all 16 loads issued before any LDS write (keep MLP high).
    float4 v[16];
    #pragma unroll
    for (int i = 0; i < 16; ++i) {
        const int n = 4 * i + w;
        v[i] = *(const float4*)&xs[(size_t)n * CDIM + l * 4];
    }
    #pragma unroll
    for (int i = 0; i < 16; ++i) {
        const int n = 4 * i + w;
        f16x4 p = {(_Float16)v[i].x, (_Float16)v[i].y, (_Float16)v[i].z, (_Float16)v[i].w};
        *(f16x4*)&lds[n * 256 + ((l ^ (n >> 3)) << 2)] = p;
    }
    __syncthreads();

    // Phase B: per q-instr the wave's 64 stores are byte-contiguous (1 KiB).
    const int kk8 = (l & 7);
    _Float16* dst = xt + ((size_t)(sb * 64 + kb) * CDIM + cb * 256) * 64;
    #pragma unroll
    for (int q = 0; q < 8; ++q) {
        const int cw = 64 * w + 8 * q + (l >> 3);
        const int c4s = (cw >> 2) ^ kk8, c2 = cw & 3;
        const int base = (c4s << 2) + c2 + kk8 * 8 * 256;
        f16x8 o;
        #pragma unroll
        for (int j = 0; j < 8; ++j)
            o[j] = lds[base + j * 256];
        *(f16x8*)&dst[(size_t)cw * 64 + kk8 * 8] = o;
    }
}

// ---------------------------------------------------------------------------
// Gram (symmetric, K-split 3): GPh[split(3)][sb] = xt(k-range)^T xt(k-range).
// Only the 10 upper tiles (ti<=tj) computed; off-diag mirrored with
// contiguous f16x4 stores. 480 blocks, makespan 1.33W. 2-phase pipeline.
// ---------------------------------------------------------------------------
__global__ __launch_bounds__(256) void gram_kernel(const _Float16* __restrict__ xt,
                                                   _Float16* __restrict__ GPh) {
    const int id = blockIdx.x;                  // 480
    const int vid = (id & 7) * 60 + (id >> 3);  // XCD-bijective
    const int sb = vid / 30, r30 = vid % 30;
    const int split = r30 / 10, tidx = r30 % 10;
    const int ti = (tidx >= 4) + (tidx >= 7) + (tidx >= 9);
    const int tj = tidx + ti - ((ti == 0) ? 0 : (ti == 1) ? 4 : (ti == 2) ? 7 : 9);
    const int I0 = ti * 128, J0 = tj * 128;
    const int kbeg = (split * 64) / 3, kend = ((split + 1) * 64) / 3;
    const _Float16* xb = xt + (size_t)sb * CDIM * NTOK;

    __shared__ _Float16 Ih[2][128 * 64];
    __shared__ _Float16 Jh[2][128 * 64];

    const int t = threadIdx.x, w = t >> 6, l = t & 63;
    const int wm = w >> 1, wn = w & 1, l15 = l & 15, lk = l >> 4;
    const int colr = w * 8 + (l >> 3), pos = l & 7;

    f32x4 acc[4][4];
    #pragma unroll
    for (int f = 0; f < 4; ++f)
        #pragma unroll
        for (int g = 0; g < 4; ++g) acc[f][g] = (f32x4)(0.0f);

    auto STAGE = [&](int bufi, int it) {
        const _Float16* kb = xb + (size_t)it * CDIM * 64;
        #pragma unroll
        for (int r = 0; r < 4; ++r) {
            const int colw = r * 32 + colr;
            const int swz = ((pos ^ (colw & 7)) << 3);
            gload_lds16(kb + (size_t)(I0 + colw) * 64 + swz, &Ih[bufi][r * 2048 + w * 512]);
            gload_lds16(kb + (size_t)(J0 + colw) * 64 + swz, &Jh[bufi][r * 2048 + w * 512]);
        }
    };

    STAGE(0, kbeg);
    for (int it = kbeg; it < kend; ++it) {
        const int cur = (it - kbeg) & 1;
        if (it < kend - 1) {
            STAGE(cur ^ 1, it + 1);
            asm volatile("s_waitcnt vmcnt(8)" ::: "memory");
        } else {
            asm volatile("s_waitcnt vmcnt(0)" ::: "memory");
        }
        __builtin_amdgcn_s_barrier();

        const _Float16* Ib = &Ih[cur][0];
        const _Float16* Jb = &Jh[cur][0];
        __builtin_amdgcn_s_setprio(1);
        #pragma unroll
        for (int ks = 0; ks < 2; ++ks) {
            f16x8 a[4], bb[4];
            #pragma unroll
            for (int f = 0; f < 4; ++f) {
                const int i = wm * 64 + f * 16 + l15;
                a[f] = *(const f16x8*)&Ib[i * 64 + ((ks * 4 + lk) ^ (i & 7)) * 8];
            }
            #pragma unroll
            for (int g = 0; g < 4; ++g) {
                const int j = wn * 64 + g * 16 + l15;
                bb[g] = *(const f16x8*)&Jb[j * 64 + ((ks * 4 + lk) ^ (j & 7)) * 8];
            }
            #pragma unroll
            for (int f = 0; f < 4; ++f)
                #pragma unroll
                for (int g = 0; g < 4; ++g)
                    acc[f][g] = __builtin_amdgcn_mfma_f32_16x16x32_f16(a[f], bb[g], acc[f][g], 0, 0, 0);
        }
        __builtin_amdgcn_s_setprio(0);
        __builtin_amdgcn_s_barrier();
    }

    _Float16* Gout = GPh + ((size_t)split * 16 + sb) * CDIM * CDIM;
    #pragma unroll
    for (int f = 0; f < 4; ++f)
        #pragma unroll
        for (int g = 0; g < 4; ++g) {
            const int row0 = I0 + wm * 64 + f * 16 + lk * 4;
            const int col  = J0 + wn * 64 + g * 16 + l15;
            #pragma unroll
            for (int r = 0; r < 4; ++r)
                Gout[(size_t)(row0 + r) * CDIM + col] = (_Float16)acc[f][g][r];
            if (ti != tj) {
                f16x4 m = {(_Float16)acc[f][g][0], (_Float16)acc[f][g][1],
                           (_Float16)acc[f][g][2], (_Float16)acc[f][g][3]};
                *(f16x4*)&Gout[(size_t)col * CDIM + row0] = m;
            }
        }
}

// ---------------------------------------------------------------------------
// T-partials: TP[ks2][sb] = (GPh0+GPh1+GPh2)(k-range) @ Wv, single fp16 MFMA.
// ---------------------------------------------------------------------------
__global__ __launch_bounds__(256) void t_kernel(const _Float16* __restrict__ GPh,
                                                const _Float16* __restrict__ wvt,
                                                _Float16* __restrict__ TP) {
    const int id = blockIdx.x;                  // 512
    const int vid = (id & 7) * 64 + (id >> 3);
    const int sb = vid >> 5, rest = vid & 31;
    const int ks2 = rest >> 4, tile = rest & 15;
    const int s = sb >> 3;
    const int I0 = (tile >> 2) * 128, J0 = (tile & 3) * 128;
    const _Float16* G0 = GPh + (size_t)sb * CDIM * CDIM;
    const _Float16* G1 = GPh + ((size_t)16 + sb) * CDIM * CDIM;
    const _Float16* G2 = GPh + ((size_t)32 + sb) * CDIM * CDIM;
    const _Float16* Bv = wvt + (size_t)s * CDIM * CDIM;

    __shared__ _Float16 Ah[128 * 64];
    __shared__ _Float16 Jh[128 * 64];

    const int t = threadIdx.x, w = t >> 6, l = t & 63;
    const int wm = w >> 1, wn = w & 1, l15 = l & 15, lk = l >> 4;
    const int colr = w * 8 + (l >> 3), pos = l & 7;

    f32x4 acc[4][4];
    #pragma unroll
    for (int f = 0; f < 4; ++f)
        #pragma unroll
        for (int g = 0; g < 4; ++g) acc[f][g] = (f32x4)(0.0f);

    for (int it = 0; it < 4; ++it) {
        const int k0 = ks2 * 256 + it * 64;
        __syncthreads();
        #pragma unroll
        for (int r = 0; r < 4; ++r) {
            const int col = r * 32 + colr;
            const int swz = ((pos ^ (col & 7)) << 3);
            gload_lds16(Bv + (size_t)(J0 + col) * CDIM + k0 + swz, &Jh[r * 2048 + w * 512]);
        }
        #pragma unroll
        for (int r = 0; r < 4; ++r) {
            const int i = r * 32 + (t >> 3), ch = t & 7;
            const size_t off = (size_t)(I0 + i) * CDIM + k0 + ch * 8;
            f16x8 a0 = *(const f16x8*)&G0[off];
            f16x8 a1 = *(const f16x8*)&G1[off];
            f16x8 a2 = *(const f16x8*)&G2[off];
            f16x8 sum = (a0 + a1) + a2;
            *(f16x8*)&Ah[i * 64 + ((ch ^ (i & 7)) << 3)] = sum;
        }
        __syncthreads();
        __builtin_amdgcn_s_setprio(1);
        #pragma unroll
        for (int ks = 0; ks < 2; ++ks) {
            f16x8 a[4], bb[4];
            #pragma unroll
            for (int f = 0; f < 4; ++f) {
                const int i = wm * 64 + f * 16 + l15;
                a[f] = *(const f16x8*)&Ah[i * 64 + ((ks * 4 + lk) ^ (i & 7)) * 8];
            }
            #pragma unroll
            for (int g = 0; g < 4; ++g) {
                const int j = wn * 64 + g * 16 + l15;
                bb[g] = *(const f16x8*)&Jh[j * 64 + ((ks * 4 + lk) ^ (j & 7)) * 8];
            }
            #pragma unroll
            for (int f = 0; f < 4; ++f)
                #pragma unroll
                for (int g = 0; g < 4; ++g)
                    acc[f][g] = __builtin_amdgcn_mfma_f32_16x16x32_f16(a[f], bb[g], acc[f][g], 0, 0, 0);
        }
        __builtin_amdgcn_s_setprio(0);
    }

    _Float16* Tb = TP + ((size_t)ks2 * 16 + sb) * CDIM * CDIM;
    #pragma unroll
    for (int f = 0; f < 4; ++f)
        #pragma unroll
        for (int g = 0; g < 4; ++g) {
            const int row0 = I0 + wm * 64 + f * 16 + lk * 4;
            const int col  = J0 + wn * 64 + g * 16 + l15;
            #pragma unroll
            for (int r = 0; r < 4; ++r)
                Tb[(size_t)(row0 + r) * CDIM + col] = (_Float16)acc[f][g][r];
        }
}

// ---------------------------------------------------------------------------
// ctx GEMM, K-split by 4: CP[kq][sb][h] = partial Wk_h^T (TP0+TP1)_h
// ---------------------------------------------------------------------------
__global__ __launch_bounds__(256) void ctx_gemm_kernel(const _Float16* __restrict__ TP,
                                                       const float* __restrict__ Wkv1,
                                                       const float* __restrict__ Wkv2,
                                                       float* __restrict__ CP) {
    const int h = blockIdx.x, sb = blockIdx.y, kq = blockIdx.z;
    const int s = sb >> 3;
    const float* W  = (s == 0 ? Wkv1 : Wkv2);
    const _Float16* T0 = TP + (size_t)sb * CDIM * CDIM;
    const _Float16* T1 = TP + ((size_t)16 + sb) * CDIM * CDIM;

    __shared__ float Kt[64][65];
    __shared__ float Tt[64][65];

    const int t = threadIdx.x;
    const int td = t >> 4, te = t & 15;
    float acc[4][4] = {};

    for (int it = 0; it < 2; ++it) {
        const int kc = kq * 128 + it * 64;
        __syncthreads();
        for (int i = 0; i < 16; ++i) {
            const int idx = t + i * 256;
            const int r = idx >> 6, cc = idx & 63;
            Kt[r][cc] = W[(size_t)(kc + r) * (2 * CDIM) + h * HD + cc];
            Tt[r][cc] = (float)T0[(size_t)(kc + r) * CDIM + h * HD + cc]
                      + (float)T1[(size_t)(kc + r) * CDIM + h * HD + cc];
        }
        __syncthreads();
        for (int k = 0; k < 64; ++k) {
            float a[4], bb[4];
            #pragma unroll
            for (int i = 0; i < 4; ++i) a[i] = Kt[k][td * 4 + i];
            #pragma unroll
            for (int j = 0; j < 4; ++j) bb[j] = Tt[k][te * 4 + j];
            #pragma unroll
            for (int i = 0; i < 4; ++i)
                #pragma unroll
                for (int j = 0; j < 4; ++j) acc[i][j] += a[i] * bb[j];
        }
    }
    float* out = CP + (size_t)(((kq * 16 + sb) * HEADS) + h) * HD * HD;
    for (int i = 0; i < 4; ++i)
        for (int j = 0; j < 4; ++j)
            out[(size_t)(td * 4 + i) * HD + te * 4 + j] = acc[i][j];
}

// ---------------------------------------------------------------------------
// ctx finish: sum 4 partials, scale, softmax over d -> smT fp16 [sb][h][e][d]
// ---------------------------------------------------------------------------
__global__ __launch_bounds__(256) void ctx_fin_kernel(const float* __restrict__ CP,
                                                      _Float16* __restrict__ smT) {
    const int h = blockIdx.x, sb = blockIdx.y;

    __shared__ float ctxs[64][65];
    __shared__ float mred[64], sred[64];

    const int t = threadIdx.x;
    const float scale = 0.125f;
    #pragma unroll
    for (int i = 0; i < 4; ++i) {
        const int idx4 = t + i * 256;
        const int d = idx4 >> 4, e4 = idx4 & 15;
        f32x4 sum = (f32x4)(0.0f);
        #pragma unroll
        for (int kq = 0; kq < 4; ++kq) {
            const float* p = CP + (size_t)(((kq * 16 + sb) * HEADS) + h) * HD * HD;
            f32x4 v = *(const f32x4*)&p[d * HD + e4 * 4];
            sum += v;
        }
        *(f32x4*)&ctxs[d][e4 * 4] = sum * scale;
    }
    __syncthreads();
    if (t < 64) {
        float m = -1e30f;
        for (int d = 0; d < 64; ++d) m = fmaxf(m, ctxs[d][t]);
        float ssum = 0.f;
        for (int d = 0; d < 64; ++d) ssum += expf(ctxs[d][t] - m);
        mred[t] = m;
        sred[t] = 1.0f / ssum;
    }
    __syncthreads();
    _Float16* smout = smT + (size_t)(sb * HEADS + h) * HD * HD;   // [e][d]
    #pragma unroll
    for (int i = 0; i < 16; ++i) {
        const int idx = t + i * 256;
        const int e = idx >> 6, d = idx & 63;
        smout[e * HD + d] = (_Float16)(expf(ctxs[d][e] - mred[e]) * sred[e]);
    }
}

// ---------------------------------------------------------------------------
// out: out_s[n, h*64+e] = sum_d x_s[n, h*64+d] * sm[1-s][h][d][e], fp16 MFMA.
// Epilogue: LDS-staged (padded stride 68) -> coalesced float4 stores
// (4x256B segments/instr, 4 instrs/thread vs 32 scalar). LDS reused.
// ---------------------------------------------------------------------------
__global__ __launch_bounds__(256) void out_kernel(const float* __restrict__ x1,
                                                  const float* __restrict__ x2,
                                                  const _Float16* __restrict__ xt,
                                                  const int use_xt,
                                                  const _Float16* __restrict__ smT,
                                                  float* __restrict__ out) {
    const int id = blockIdx.x;                   // 4096
    const int vid = (id & 7) * 512 + (id >> 3);  // h-groups co-XCD
    const int h = vid & 7, nt = (vid >> 3) & 31, sb = vid >> 8;
    const int s = sb >> 3, b = sb & 7;
    const float* xs = (s ? x2 : x1) + (size_t)b * NTOK * CDIM;
    const _Float16* sm = smT + (size_t)((((1 - s) * 8 + b) * HEADS) + h) * HD * HD;
    const int n0 = nt * 128;

    // 24 KiB shared: Axt 16K + Bsm 8K during MFMA; reused as Ot (17 KiB
    // f32 [64][68]) for the two-pass coalescing epilogue.
    __shared__ __align__(16) char shraw[24576];
    _Float16* Axt = (_Float16*)shraw;            // [n][d] swizzled, 16 KiB
    _Float16* Bsm = (_Float16*)(shraw + 16384);  // [e][d] swizzled, 8 KiB
    float*    Ot  = (float*)shraw;               // [64][68] epilogue stage

    const int t = threadIdx.x, w = t >> 6, l = t & 63;
    const int l15 = l & 15, lk = l >> 4;

    // B stage via gl_lds (2 rounds)
    #pragma unroll
    for (int r = 0; r < 2; ++r) {
        const int e = r * 32 + w * 8 + (l >> 3), pos = l & 7;
        gload_lds16(sm + (size_t)e * HD + ((pos ^ (e & 7)) << 3), &Bsm[r * 2048 + w * 512]);
    }

    if (use_xt) {
        const int kb  = t >> 7;
        const int cc  = (t >> 1) & 63;
        const int kk0 = (t & 1) * 32;
        const _Float16* src = xt + ((size_t)(sb * 64 + nt * 2 + kb) * CDIM + h * HD + cc) * 64 + kk0;
        f16x8 vv[4];
        #pragma unroll
        for (int i = 0; i < 4; ++i)
            vv[i] = *(const f16x8*)(src + 8 * i);
        const int chunk = ((cc >> 3) << 4);
        #pragma unroll
        for (int i = 0; i < 4; ++i) {
            #pragma unroll
            for (int j = 0; j < 8; ++j) {
                const int row = kb * 64 + kk0 + 8 * i + j;   // row&7 == j
                const int byte = row * 128 + (chunk ^ (j << 4)) + (cc & 7) * 2;
                *(_Float16*)((char*)Axt + byte) = vv[i][j];
            }
        }
    } else {
        #pragma unroll
        for (int p = 0; p < 8; ++p) {
            const int row = p * 16 + (t >> 4), f4c = t & 15;
            float4 u = *(const float4*)&xs[(size_t)(n0 + row) * CDIM + h * HD + f4c * 4];
            f16x4 q = {(_Float16)u.x, (_Float16)u.y, (_Float16)u.z, (_Float16)u.w};
            const int byte = row * 128 + (((f4c >> 1) ^ (row & 7)) << 4) + ((f4c & 1) << 3);
            *(f16x4*)((char*)Axt + byte) = q;
        }
    }
    __syncthreads();

    f32x4 acc[2][4];
    #pragma unroll
    for (int m = 0; m < 2; ++m)
        #pragma unroll
        for (int g = 0; g < 4; ++g) acc[m][g] = (f32x4)(0.0f);

    #pragma unroll
    for (int ks = 0; ks < 2; ++ks) {
        f16x8 a[2], bb[4];
        #pragma unroll
        for (int m = 0; m < 2; ++m) {
            const int row = w * 32 + m * 16 + l15;
            a[m] = *(const f16x8*)((char*)Axt + row * 128 + (((ks * 4 + lk) ^ (row & 7)) << 4));
        }
        #pragma unroll
        for (int g = 0; g < 4; ++g) {
            const int e = g * 16 + l15;
            bb[g] = *(const f16x8*)((char*)Bsm + e * 128 + (((ks * 4 + lk) ^ (e & 7)) << 4));
        }
        #pragma unroll
        for (int m = 0; m < 2; ++m)
            #pragma unroll
            for (int g = 0; g < 4; ++g)
                acc[m][g] = __builtin_amdgcn_mfma_f32_16x16x32_f16(a[m], bb[g], acc[m][g], 0, 0, 0);
    }

    // Epilogue: 2 passes of 64 rows through LDS, coalesced float4 stores.
    float* ob = out + (size_t)s * (8ULL * NTOK * CDIM) + (size_t)b * NTOK * CDIM;
    #pragma unroll
    for (int p = 0; p < 2; ++p) {
        __syncthreads();
        if ((w >> 1) == p) {
            #pragma unroll
            for (int m = 0; m < 2; ++m)
                #pragma unroll
                for (int g = 0; g < 4; ++g)
                    #pragma unroll
                    for (int r = 0; r < 4; ++r) {
                        const int row = (w & 1) * 32 + m * 16 + lk * 4 + r;
                        Ot[row * 68 + g * 16 + l15] = acc[m][g][r];
                    }
        }
        __syncthreads();
        #pragma unroll
        for (int q = 0; q < 4; ++q) {
            const int idx = q * 256 + t;
            const int row = idx >> 4, c4 = idx & 15;
            float4 v4 = *(float4*)&Ot[row * 68 + c4 * 4];
            *(float4*)&ob[(size_t)(n0 + p * 64 + row) * CDIM + h * HD + c4 * 4] = v4;
        }
    }
}

// ---------------------------------------------------------------------------
extern "C" void kernel_launch(void* const* d_in, const int* in_sizes, int n_in,
                              void* d_out, int out_size, void* d_ws, size_t ws_size,
                              hipStream_t stream) {
    const float* x1   = (const float*)d_in[0];
    const float* x2   = (const float*)d_in[1];
    const float* Wkv1 = (const float*)d_in[2];
    const float* Wkv2 = (const float*)d_in[3];
    float* out = (float*)d_out;

    // Scratch: XT 64Mi, WVT 1Mi, GPh 24Mi (3 partials), TP 16Mi, CP 8Mi, SMT 1Mi.
    const size_t NEED = 120586240;  // ~115 MiB
    _Float16 *XT, *WVT, *GPh, *TP, *SMT;
    float* CP;
    int use_xt;
    if (ws_size >= NEED) {
        char* base = (char*)d_ws;
        XT  = (_Float16*)(base + 0);
        WVT = (_Float16*)(base + 67108864);
        GPh = (_Float16*)(base + 68157440);
        TP  = (_Float16*)(base + 93323264);
        CP  = (float*)  (base + 110100480);
        SMT = (_Float16*)(base + 118489088);
        use_xt = 1;
    } else {
        char* base = (char*)d_out;
        XT  = (_Float16*)(base + 0);
        WVT = (_Float16*)(base + 67108864);
        GPh = (_Float16*)(base + 68157440);
        TP  = (_Float16*)(base + 93323264);
        CP  = (float*)  (base + 110100480);
        SMT = (_Float16*)d_ws;
        use_xt = 0;
    }

    hipLaunchKernelGGL(xpose_kernel, dim3(66, 2, 16), dim3(256), 0, stream,
                       x1, x2, Wkv1, Wkv2, XT, WVT);
    hipLaunchKernelGGL(gram_kernel, dim3(480), dim3(256), 0, stream, XT, GPh);
    hipLaunchKernelGGL(t_kernel, dim3(512), dim3(256), 0, stream, GPh, WVT, TP);
    hipLaunchKernelGGL(ctx_gemm_kernel, dim3(8, 16, 4), dim3(256), 0, stream,
                       TP, Wkv1, Wkv2, CP);
    hipLaunchKernelGGL(ctx_fin_kernel, dim3(8, 16), dim3(256), 0, stream, CP, SMT);
    hipLaunchKernelGGL(out_kernel, dim3(4096), dim3(256), 0, stream,
                       x1, x2, XT, use_xt, SMT, out);
}